// Round 2
// baseline (940.898 us; speedup 1.0000x reference)
//
#include <hip/hip_runtime.h>
#include <hip/hip_bf16.h>

typedef __attribute__((ext_vector_type(4))) float f32x4;
typedef __attribute__((ext_vector_type(8))) short bf16x8;

#define NTOK 65536
#define DMODEL 256
#define DFF 1024
#define NH 8
#define HD 32
#define SSP 128
#define TLEN 128
#define SCALE 0.17677669529663687f  /* 1/sqrt(32) */

__device__ __forceinline__ float bf2f(unsigned short u) {
    return __builtin_bit_cast(float, (unsigned int)u << 16);
}
__device__ __forceinline__ unsigned short f2bf(float f) {
    unsigned int u = __builtin_bit_cast(unsigned int, f);
    unsigned int r = u + 0x7fffu + ((u >> 16) & 1u);
    return (unsigned short)(r >> 16);
}
__device__ __forceinline__ void gload_lds16(const void* g, void* l) {
    __builtin_amdgcn_global_load_lds((const __attribute__((address_space(1))) void*)g,
                                     (__attribute__((address_space(3))) void*)l, 16, 0, 0);
}

// ---------------- weight fp32 -> bf16 conversion (all 6 mats, 1,048,576 elems) --------
__global__ __launch_bounds__(256)
void cvt_w(const float* __restrict__ a, const float* __restrict__ b,
           const float* __restrict__ c, const float* __restrict__ d,
           const float* __restrict__ e, const float* __restrict__ f,
           unsigned short* __restrict__ o)
{
    int i = blockIdx.x * 256 + threadIdx.x;
    float v;
    if      (i < 196608)  v = a[i];
    else if (i < 262144)  v = b[i - 196608];
    else if (i < 458752)  v = c[i - 262144];
    else if (i < 524288)  v = d[i - 458752];
    else if (i < 786432)  v = e[i - 524288];
    else                  v = f[i - 786432];
    o[i] = f2bf(v);
}

// ---------------- RMSNorm: one block per row of 256 ----------------------------------
__global__ __launch_bounds__(256)
void rmsnorm_k(const float* __restrict__ x, const float* __restrict__ g,
               unsigned short* __restrict__ out)
{
    const int row = blockIdx.x;
    const int tid = threadIdx.x;
    float v = x[(size_t)row * DMODEL + tid];
    float s = v * v;
    #pragma unroll
    for (int o = 32; o > 0; o >>= 1) s += __shfl_down(s, o);
    __shared__ float ws[4];
    __shared__ float rinv;
    const int wave = tid >> 6, lane = tid & 63;
    if (lane == 0) ws[wave] = s;
    __syncthreads();
    if (tid == 0) rinv = rsqrtf((ws[0] + ws[1] + ws[2] + ws[3]) * (1.0f / DMODEL) + 1.1920929e-7f);
    __syncthreads();
    out[(size_t)row * DMODEL + tid] = f2bf(v * rinv * g[tid]);
}

// ---------------- GEMM: C[M,N] = A[M,K] * W[N,K]^T + bias (both bf16 row-major, K contig)
// EPI 0: bias -> bf16 out;  EPI 1: bias+GELU -> bf16 out;  EPI 2: bias + in-place fp32 residual add
template<int EPI>
__global__ __launch_bounds__(256)
void gemm_bt(const unsigned short* __restrict__ A,
             const unsigned short* __restrict__ W,
             const float* __restrict__ bias,
             unsigned short* __restrict__ Cb,
             float* __restrict__ Cf,
             int M, int N, int K)
{
    __shared__ unsigned short As[128 * 32];
    __shared__ unsigned short Bs[128 * 32];
    const int tid = threadIdx.x;
    const int wave = tid >> 6, lane = tid & 63;
    const int wr = wave >> 1, wc = wave & 1;
    const int row0 = blockIdx.x * 128, col0 = blockIdx.y * 128;

    f32x4 acc[4][4];
    #pragma unroll
    for (int i = 0; i < 4; i++)
        #pragma unroll
        for (int j = 0; j < 4; j++)
            acc[i][j] = (f32x4){0.f, 0.f, 0.f, 0.f};

    const int prow = tid >> 2;           // rows 0..63 (pass 0)
    const int pk   = (tid & 3) * 16;     // byte offset within 64-byte row

    for (int k0 = 0; k0 < K; k0 += 32) {
        #pragma unroll
        for (int pass = 0; pass < 2; pass++) {
            const int row = pass * 64 + prow;
            const char* ga = (const char*)A + ((size_t)(row0 + row) * K + k0) * 2 + pk;
            const char* gb = (const char*)W + ((size_t)(col0 + row) * K + k0) * 2 + pk;
            char* la = (char*)As + pass * 4096 + wave * 1024;
            char* lb = (char*)Bs + pass * 4096 + wave * 1024;
            gload_lds16(ga, la);
            gload_lds16(gb, lb);
        }
        __syncthreads();
        const int fr  = lane & 15;
        const int fko = (lane >> 4) * 8;
        bf16x8 af[4], bw[4];
        #pragma unroll
        for (int i = 0; i < 4; i++) af[i] = *(const bf16x8*)&As[(wr * 64 + i * 16 + fr) * 32 + fko];
        #pragma unroll
        for (int j = 0; j < 4; j++) bw[j] = *(const bf16x8*)&Bs[(wc * 64 + j * 16 + fr) * 32 + fko];
        #pragma unroll
        for (int i = 0; i < 4; i++)
            #pragma unroll
            for (int j = 0; j < 4; j++)
                acc[i][j] = __builtin_amdgcn_mfma_f32_16x16x32_bf16(af[i], bw[j], acc[i][j], 0, 0, 0);
        __syncthreads();
    }

    const int cr = (lane >> 4) * 4, cc = lane & 15;
    #pragma unroll
    for (int i = 0; i < 4; i++) {
        #pragma unroll
        for (int j = 0; j < 4; j++) {
            const int col = col0 + wc * 64 + j * 16 + cc;
            const float bv = bias[col];
            #pragma unroll
            for (int r = 0; r < 4; r++) {
                const int row = row0 + wr * 64 + i * 16 + cr + r;
                float v = acc[i][j][r] + bv;
                if constexpr (EPI == 1) v = 0.5f * v * (1.0f + erff(v * 0.70710678118654752f));
                if constexpr (EPI == 2) {
                    Cf[(size_t)row * N + col] += v;
                } else {
                    Cb[(size_t)row * N + col] = f2bf(v);
                }
            }
        }
    }
}

// ---------------- spatial attention: one block per (bt, head), 128x128, MFMA ----------
__global__ __launch_bounds__(256)
void attn_spatial(const unsigned short* __restrict__ qkv,  // [NTOK][768]
                  const int* __restrict__ coords,          // [128][2]
                  unsigned short* __restrict__ out)        // [NTOK][256]
{
    __shared__ unsigned short Qs[128 * 32];
    __shared__ unsigned short Ks[128 * 32];
    __shared__ unsigned short Vt[32 * 136];   // V^T, padded rows
    __shared__ float Ps[64 * 128];            // scores for one 64-row half
    __shared__ int cx[128], cy[128];

    const int bt = blockIdx.x, h = blockIdx.y;
    const int tid = threadIdx.x, wave = tid >> 6, lane = tid & 63;
    const size_t base = (size_t)bt * SSP * 768 + (size_t)h * HD;

    {   // stage Q,K (row-major [128][32]) and V transposed
        const int rr = tid >> 1, cb = (tid & 1) * 16;
        const unsigned short* p = qkv + base + (size_t)rr * 768 + cb;
        *(bf16x8*)&Qs[rr * 32 + cb]     = *(const bf16x8*)p;
        *(bf16x8*)&Qs[rr * 32 + cb + 8] = *(const bf16x8*)(p + 8);
        p += 256;
        *(bf16x8*)&Ks[rr * 32 + cb]     = *(const bf16x8*)p;
        *(bf16x8*)&Ks[rr * 32 + cb + 8] = *(const bf16x8*)(p + 8);
        p += 256;
        bf16x8 v0 = *(const bf16x8*)p, v1 = *(const bf16x8*)(p + 8);
        #pragma unroll
        for (int e = 0; e < 8; e++) {
            Vt[(cb + e) * 136 + rr]     = (unsigned short)v0[e];
            Vt[(cb + 8 + e) * 136 + rr] = (unsigned short)v1[e];
        }
        if (tid < 128) { cx[tid] = coords[2 * tid]; cy[tid] = coords[2 * tid + 1]; }
    }
    __syncthreads();

    const int fr = lane & 15, fko = (lane >> 4) * 8;
    const int cr = (lane >> 4) * 4, cc = lane & 15;

    for (int half = 0; half < 2; half++) {
        const int rbase = half * 64;
        bf16x8 aq = *(const bf16x8*)&Qs[(rbase + wave * 16 + fr) * 32 + fko];
        #pragma unroll
        for (int tj = 0; tj < 8; tj++) {
            bf16x8 bk = *(const bf16x8*)&Ks[(tj * 16 + fr) * 32 + fko];
            f32x4 s = (f32x4){0.f, 0.f, 0.f, 0.f};
            s = __builtin_amdgcn_mfma_f32_16x16x32_bf16(aq, bk, s, 0, 0, 0);
            #pragma unroll
            for (int r = 0; r < 4; r++) {
                const int i = rbase + wave * 16 + cr + r;
                const int j = tj * 16 + cc;
                int dx = cx[i] - cx[j]; dx = dx < 0 ? -dx : dx;
                int dy = cy[i] - cy[j]; dy = dy < 0 ? -dy : dy;
                const int ch = dx > dy ? dx : dy;
                Ps[(wave * 16 + cr + r) * 128 + j] = (ch > 4) ? -1e9f : s[r] * SCALE;
            }
        }
        __syncthreads();
        if (tid < 64) {   // fp32 row softmax
            float* pr = &Ps[tid * 128];
            float mx = -1e30f;
            for (int j = 0; j < 128; j++) mx = fmaxf(mx, pr[j]);
            float sm = 0.f;
            for (int j = 0; j < 128; j++) { float e = __expf(pr[j] - mx); pr[j] = e; sm += e; }
            const float inv = 1.0f / sm;
            for (int j = 0; j < 128; j++) pr[j] *= inv;
        }
        __syncthreads();
        #pragma unroll
        for (int td = 0; td < 2; td++) {
            f32x4 o = (f32x4){0.f, 0.f, 0.f, 0.f};
            #pragma unroll
            for (int kk = 0; kk < 4; kk++) {
                const float* pp = &Ps[(wave * 16 + fr) * 128 + kk * 32 + fko];
                bf16x8 pa;
                #pragma unroll
                for (int e = 0; e < 8; e++) pa[e] = (short)f2bf(pp[e]);
                bf16x8 bv = *(const bf16x8*)&Vt[(td * 16 + fr) * 136 + kk * 32 + fko];
                o = __builtin_amdgcn_mfma_f32_16x16x32_bf16(pa, bv, o, 0, 0, 0);
            }
            #pragma unroll
            for (int r = 0; r < 4; r++) {
                const int i = rbase + wave * 16 + cr + r;
                const int d = td * 16 + cc;
                out[((size_t)(bt * SSP + i)) * DMODEL + h * HD + d] = f2bf(o[r]);
            }
        }
        __syncthreads();
    }
}

// ---------------- temporal attention: window of <=4 keys, per-thread scalar -----------
__device__ __forceinline__ float dot32(const float* __restrict__ qr,
                                       const unsigned short* __restrict__ Kt, int j)
{
    float a = 0.f;
    #pragma unroll
    for (int d = 0; d < 32; d++) a += qr[d] * bf2f(Kt[d * 128 + j]);
    return a;
}

__global__ __launch_bounds__(128)
void attn_temporal(const unsigned short* __restrict__ qkv,  // [NTOK][768]
                   unsigned short* __restrict__ out)        // [NTOK][256]
{
    __shared__ unsigned short Qt[32 * 128], Kt[32 * 128], Vt[32 * 128];  // transposed [d][t]
    const int bs = blockIdx.x, h = blockIdx.y;
    const int b = bs >> 7, sp = bs & 127;
    const int tid = threadIdx.x;   // t index 0..127
    const size_t rb = ((size_t)b * 16384 + (size_t)tid * 128 + sp) * 768 + (size_t)h * HD;
    #pragma unroll
    for (int c = 0; c < 4; c++) {
        bf16x8 q = *(const bf16x8*)(qkv + rb + c * 8);
        bf16x8 k = *(const bf16x8*)(qkv + rb + 256 + c * 8);
        bf16x8 v = *(const bf16x8*)(qkv + rb + 512 + c * 8);
        #pragma unroll
        for (int e = 0; e < 8; e++) {
            const int d = c * 8 + e;
            Qt[d * 128 + tid] = (unsigned short)q[e];
            Kt[d * 128 + tid] = (unsigned short)k[e];
            Vt[d * 128 + tid] = (unsigned short)v[e];
        }
    }
    __syncthreads();

    const int i = tid;
    float qr[32];
    #pragma unroll
    for (int d = 0; d < 32; d++) qr[d] = bf2f(Qt[d * 128 + i]);

    float s0 = -1e30f, s1 = -1e30f, s2 = -1e30f;
    if (i >= 3) s0 = dot32(qr, Kt, i - 3) * SCALE;
    if (i >= 2) s1 = dot32(qr, Kt, i - 2) * SCALE;
    if (i >= 1) s2 = dot32(qr, Kt, i - 1) * SCALE;
    const float s3 = dot32(qr, Kt, i) * SCALE;

    const float mx = fmaxf(fmaxf(s0, s1), fmaxf(s2, s3));
    const float p0 = __expf(s0 - mx), p1 = __expf(s1 - mx), p2 = __expf(s2 - mx), p3 = __expf(s3 - mx);
    const float inv = 1.0f / (p0 + p1 + p2 + p3);
    const int j0 = i >= 3 ? i - 3 : 0;
    const int j1 = i >= 2 ? i - 2 : 0;
    const int j2 = i >= 1 ? i - 1 : 0;
    const size_t ob = ((size_t)b * 16384 + (size_t)i * 128 + sp) * DMODEL + (size_t)h * HD;
    #pragma unroll
    for (int d = 0; d < 32; d++) {
        const float o = (p0 * bf2f(Vt[d * 128 + j0]) + p1 * bf2f(Vt[d * 128 + j1]) +
                         p2 * bf2f(Vt[d * 128 + j2]) + p3 * bf2f(Vt[d * 128 + i])) * inv;
        out[ob + d] = f2bf(o);
    }
}

// --------------------------------------------------------------------------------------
extern "C" void kernel_launch(void* const* d_in, const int* in_sizes, int n_in,
                              void* d_out, int out_size, void* d_ws, size_t ws_size,
                              hipStream_t stream)
{
    const int*   coords = (const int*)d_in[1];
    const float* Wqkv_s = (const float*)d_in[3];
    const float* bqkv_s = (const float*)d_in[4];
    const float* Wo_s   = (const float*)d_in[5];
    const float* bo_s   = (const float*)d_in[6];
    const float* Wqkv_t = (const float*)d_in[7];
    const float* bqkv_t = (const float*)d_in[8];
    const float* Wo_t   = (const float*)d_in[9];
    const float* bo_t   = (const float*)d_in[10];
    const float* g1     = (const float*)d_in[11];
    const float* g2     = (const float*)d_in[12];
    const float* g3     = (const float*)d_in[13];
    const float* W1     = (const float*)d_in[14];
    const float* b1     = (const float*)d_in[15];
    const float* W2     = (const float*)d_in[16];
    const float* b2     = (const float*)d_in[17];
    float* xo = (float*)d_out;

    char* ws = (char*)d_ws;
    unsigned short* wb  = (unsigned short*)ws;                                 // 2 MB weights
    unsigned short* xn  = (unsigned short*)(ws + (size_t)2 * 1024 * 1024);     // 32 MB norm / attn-out
    unsigned short* big = (unsigned short*)(ws + (size_t)34 * 1024 * 1024);    // 128 MB qkv / ffn-hidden

    unsigned short* wQKVs = wb;
    unsigned short* wOs   = wb + 196608;
    unsigned short* wQKVt = wb + 262144;
    unsigned short* wOt   = wb + 458752;
    unsigned short* w1b   = wb + 524288;
    unsigned short* w2b   = wb + 786432;

    // x residual lives in d_out (fp32), updated in place by EPI==2 GEMMs
    (void)hipMemcpyAsync(d_out, d_in[0], (size_t)NTOK * DMODEL * sizeof(float),
                         hipMemcpyDeviceToDevice, stream);
    cvt_w<<<4096, 256, 0, stream>>>(Wqkv_s, Wo_s, Wqkv_t, Wo_t, W1, W2, wb);

    // ---- spatial block ----
    rmsnorm_k<<<NTOK, 256, 0, stream>>>(xo, g1, xn);
    gemm_bt<0><<<dim3(512, 6), 256, 0, stream>>>(xn, wQKVs, bqkv_s, big, nullptr, NTOK, 768, 256);
    attn_spatial<<<dim3(512, 8), 256, 0, stream>>>(big, coords, xn);
    gemm_bt<2><<<dim3(512, 2), 256, 0, stream>>>(xn, wOs, bo_s, nullptr, xo, NTOK, 256, 256);

    // ---- temporal block ----
    rmsnorm_k<<<NTOK, 256, 0, stream>>>(xo, g2, xn);
    gemm_bt<0><<<dim3(512, 6), 256, 0, stream>>>(xn, wQKVt, bqkv_t, big, nullptr, NTOK, 768, 256);
    attn_temporal<<<dim3(512, 8), 128, 0, stream>>>(big, xn);
    gemm_bt<2><<<dim3(512, 2), 256, 0, stream>>>(xn, wOt, bo_t, nullptr, xo, NTOK, 256, 256);

    // ---- FFN block ----
    rmsnorm_k<<<NTOK, 256, 0, stream>>>(xo, g3, xn);
    gemm_bt<1><<<dim3(512, 8), 256, 0, stream>>>(xn, w1b, b1, big, nullptr, NTOK, 1024, 256);
    gemm_bt<2><<<dim3(512, 2), 256, 0, stream>>>(big, w2b, b2, nullptr, xo, NTOK, 256, 1024);
}

// Round 3
// 748.937 us; speedup vs baseline: 1.2563x; 1.2563x over previous
//
#include <hip/hip_runtime.h>
#include <hip/hip_bf16.h>

typedef __attribute__((ext_vector_type(4))) float f32x4;
typedef __attribute__((ext_vector_type(8))) short bf16x8;

#define NTOK 65536
#define DMODEL 256
#define DFF 1024
#define NH 8
#define HD 32
#define SSP 128
#define TLEN 128
#define SCALE 0.17677669529663687f  /* 1/sqrt(32) */

__device__ __forceinline__ float bf2f(unsigned short u) {
    return __builtin_bit_cast(float, (unsigned int)u << 16);
}
__device__ __forceinline__ unsigned short f2bf(float f) {
    unsigned int u = __builtin_bit_cast(unsigned int, f);
    unsigned int r = u + 0x7fffu + ((u >> 16) & 1u);
    return (unsigned short)(r >> 16);
}
__device__ __forceinline__ void gload_lds16(const void* g, void* l) {
    __builtin_amdgcn_global_load_lds((const __attribute__((address_space(1))) void*)g,
                                     (__attribute__((address_space(3))) void*)l, 16, 0, 0);
}

// ---------------- weight fp32 -> bf16 conversion (all 6 mats, 1,048,576 elems) --------
__global__ __launch_bounds__(256)
void cvt_w(const float* __restrict__ a, const float* __restrict__ b,
           const float* __restrict__ c, const float* __restrict__ d,
           const float* __restrict__ e, const float* __restrict__ f,
           unsigned short* __restrict__ o)
{
    int i = blockIdx.x * 256 + threadIdx.x;
    float v;
    if      (i < 196608)  v = a[i];
    else if (i < 262144)  v = b[i - 196608];
    else if (i < 458752)  v = c[i - 262144];
    else if (i < 524288)  v = d[i - 458752];
    else if (i < 786432)  v = e[i - 524288];
    else                  v = f[i - 786432];
    o[i] = f2bf(v);
}

// ---------------- RMSNorm: one block per row of 256 ----------------------------------
__global__ __launch_bounds__(256)
void rmsnorm_k(const float* __restrict__ x, const float* __restrict__ g,
               unsigned short* __restrict__ out)
{
    const int row = blockIdx.x;
    const int tid = threadIdx.x;
    float v = x[(size_t)row * DMODEL + tid];
    float s = v * v;
    #pragma unroll
    for (int o = 32; o > 0; o >>= 1) s += __shfl_down(s, o);
    __shared__ float ws[4];
    __shared__ float rinv;
    const int wave = tid >> 6, lane = tid & 63;
    if (lane == 0) ws[wave] = s;
    __syncthreads();
    if (tid == 0) rinv = rsqrtf((ws[0] + ws[1] + ws[2] + ws[3]) * (1.0f / DMODEL) + 1.1920929e-7f);
    __syncthreads();
    out[(size_t)row * DMODEL + tid] = f2bf(v * rinv * g[tid]);
}

// ---------------- GEMM: C[M,N] = A[M,K] * W[N,K]^T + bias (both bf16 row-major, K contig)
// EPI 0: bias -> bf16 out;  EPI 1: bias+GELU -> bf16 out;  EPI 2: bias + in-place fp32 residual add
template<int EPI>
__global__ __launch_bounds__(256)
void gemm_bt(const unsigned short* __restrict__ A,
             const unsigned short* __restrict__ W,
             const float* __restrict__ bias,
             unsigned short* __restrict__ Cb,
             float* __restrict__ Cf,
             int M, int N, int K)
{
    __shared__ unsigned short As[128 * 32];
    __shared__ unsigned short Bs[128 * 32];
    const int tid = threadIdx.x;
    const int wave = tid >> 6, lane = tid & 63;
    const int wr = wave >> 1, wc = wave & 1;
    const int row0 = blockIdx.x * 128, col0 = blockIdx.y * 128;

    f32x4 acc[4][4];
    #pragma unroll
    for (int i = 0; i < 4; i++)
        #pragma unroll
        for (int j = 0; j < 4; j++)
            acc[i][j] = (f32x4){0.f, 0.f, 0.f, 0.f};

    const int prow = tid >> 2;           // rows 0..63 (pass 0)
    const int pk   = (tid & 3) * 16;     // byte offset within 64-byte row

    for (int k0 = 0; k0 < K; k0 += 32) {
        #pragma unroll
        for (int pass = 0; pass < 2; pass++) {
            const int row = pass * 64 + prow;
            const char* ga = (const char*)A + ((size_t)(row0 + row) * K + k0) * 2 + pk;
            const char* gb = (const char*)W + ((size_t)(col0 + row) * K + k0) * 2 + pk;
            char* la = (char*)As + pass * 4096 + wave * 1024;
            char* lb = (char*)Bs + pass * 4096 + wave * 1024;
            gload_lds16(ga, la);
            gload_lds16(gb, lb);
        }
        __syncthreads();
        const int fr  = lane & 15;
        const int fko = (lane >> 4) * 8;
        bf16x8 af[4], bw[4];
        #pragma unroll
        for (int i = 0; i < 4; i++) af[i] = *(const bf16x8*)&As[(wr * 64 + i * 16 + fr) * 32 + fko];
        #pragma unroll
        for (int j = 0; j < 4; j++) bw[j] = *(const bf16x8*)&Bs[(wc * 64 + j * 16 + fr) * 32 + fko];
        #pragma unroll
        for (int i = 0; i < 4; i++)
            #pragma unroll
            for (int j = 0; j < 4; j++)
                acc[i][j] = __builtin_amdgcn_mfma_f32_16x16x32_bf16(af[i], bw[j], acc[i][j], 0, 0, 0);
        __syncthreads();
    }

    const int cr = (lane >> 4) * 4, cc = lane & 15;
    #pragma unroll
    for (int i = 0; i < 4; i++) {
        #pragma unroll
        for (int j = 0; j < 4; j++) {
            const int col = col0 + wc * 64 + j * 16 + cc;
            const float bv = bias[col];
            #pragma unroll
            for (int r = 0; r < 4; r++) {
                const int row = row0 + wr * 64 + i * 16 + cr + r;
                float v = acc[i][j][r] + bv;
                if constexpr (EPI == 1) v = 0.5f * v * (1.0f + erff(v * 0.70710678118654752f));
                if constexpr (EPI == 2) {
                    Cf[(size_t)row * N + col] += v;
                } else {
                    Cb[(size_t)row * N + col] = f2bf(v);
                }
            }
        }
    }
}

// ---------------- spatial attention: one block per (bt, head), 128x128, MFMA ----------
// Scores stay in registers; row softmax via 16-lane __shfl_xor reduction (C/D layout:
// row = (lane>>4)*4+reg spread over the 16 lanes with equal lane>>4 → row lives across
// lanes sharing lane>>4, reduce with xor 1,2,4,8). P written once as bf16 to padded LDS
// (stride 132: banks (2*row + col>>1)%32, conflict-free), read back as PV A-fragment.
// Pb rows are wave-private (wave w owns rows [16w,16w+16)) → no barriers in main loop.
__global__ __launch_bounds__(256)
void attn_spatial(const unsigned short* __restrict__ qkv,  // [NTOK][768]
                  const int* __restrict__ coords,          // [128][2]
                  unsigned short* __restrict__ out)        // [NTOK][256]
{
    __shared__ unsigned short Qs[128 * 32];
    __shared__ unsigned short Ks[128 * 32];
    __shared__ unsigned short Vt[32 * 136];   // V^T, padded rows
    __shared__ unsigned short Pb[64 * 132];   // bf16 P for one 64-row half
    __shared__ int cx[128], cy[128];

    const int bt = blockIdx.x, h = blockIdx.y;
    const int tid = threadIdx.x, wave = tid >> 6, lane = tid & 63;
    const size_t base = (size_t)bt * SSP * 768 + (size_t)h * HD;

    {   // stage Q,K (row-major [128][32]) and V transposed
        const int rr = tid >> 1, cb = (tid & 1) * 16;
        const unsigned short* p = qkv + base + (size_t)rr * 768 + cb;
        *(bf16x8*)&Qs[rr * 32 + cb]     = *(const bf16x8*)p;
        *(bf16x8*)&Qs[rr * 32 + cb + 8] = *(const bf16x8*)(p + 8);
        p += 256;
        *(bf16x8*)&Ks[rr * 32 + cb]     = *(const bf16x8*)p;
        *(bf16x8*)&Ks[rr * 32 + cb + 8] = *(const bf16x8*)(p + 8);
        p += 256;
        bf16x8 v0 = *(const bf16x8*)p, v1 = *(const bf16x8*)(p + 8);
        #pragma unroll
        for (int e = 0; e < 8; e++) {
            Vt[(cb + e) * 136 + rr]     = (unsigned short)v0[e];
            Vt[(cb + 8 + e) * 136 + rr] = (unsigned short)v1[e];
        }
        if (tid < 128) { cx[tid] = coords[2 * tid]; cy[tid] = coords[2 * tid + 1]; }
    }
    __syncthreads();

    const int fr = lane & 15;        // A-frag row / C-col within tile
    const int g  = lane >> 4;        // 16-lane group
    const int fko = g * 8;           // k offset within 32

    for (int half = 0; half < 2; half++) {
        const int rbase = half * 64 + wave * 16;   // this wave's 16 q-rows
        // ---- S = Q K^T (8 tiles of 16 cols), kept in registers ----
        bf16x8 aq = *(const bf16x8*)&Qs[(rbase + fr) * 32 + fko];
        f32x4 sc[8];
        #pragma unroll
        for (int tj = 0; tj < 8; tj++) {
            bf16x8 bk = *(const bf16x8*)&Ks[(tj * 16 + fr) * 32 + fko];
            sc[tj] = __builtin_amdgcn_mfma_f32_16x16x32_bf16(aq, bk, (f32x4){0.f,0.f,0.f,0.f}, 0, 0, 0);
        }
        // ---- mask + scale + row max (rows r: i = rbase + g*4 + r) ----
        int cxi[4], cyi[4];
        #pragma unroll
        for (int r = 0; r < 4; r++) { const int i = rbase + g * 4 + r; cxi[r] = cx[i]; cyi[r] = cy[i]; }
        float m[4] = {-1e30f, -1e30f, -1e30f, -1e30f};
        #pragma unroll
        for (int tj = 0; tj < 8; tj++) {
            const int j = tj * 16 + fr;
            const int cxj = cx[j], cyj = cy[j];
            #pragma unroll
            for (int r = 0; r < 4; r++) {
                int dx = cxi[r] - cxj; dx = dx < 0 ? -dx : dx;
                int dy = cyi[r] - cyj; dy = dy < 0 ? -dy : dy;
                const float v = ((dx > dy ? dx : dy) > 4) ? -1e9f : sc[tj][r] * SCALE;
                sc[tj][r] = v;
                m[r] = fmaxf(m[r], v);
            }
        }
        #pragma unroll
        for (int r = 0; r < 4; r++) {
            #pragma unroll
            for (int o = 1; o < 16; o <<= 1) m[r] = fmaxf(m[r], __shfl_xor(m[r], o));
        }
        // ---- exp + row sum ----
        float sm[4] = {0.f, 0.f, 0.f, 0.f};
        #pragma unroll
        for (int tj = 0; tj < 8; tj++) {
            #pragma unroll
            for (int r = 0; r < 4; r++) {
                const float e = __expf(sc[tj][r] - m[r]);
                sc[tj][r] = e;
                sm[r] += e;
            }
        }
        #pragma unroll
        for (int r = 0; r < 4; r++) {
            #pragma unroll
            for (int o = 1; o < 16; o <<= 1) sm[r] += __shfl_xor(sm[r], o);
        }
        float inv[4];
        #pragma unroll
        for (int r = 0; r < 4; r++) inv[r] = 1.0f / sm[r];
        // ---- write normalized P as bf16 (wave-private rows) ----
        #pragma unroll
        for (int tj = 0; tj < 8; tj++) {
            #pragma unroll
            for (int r = 0; r < 4; r++)
                Pb[(wave * 16 + g * 4 + r) * 132 + tj * 16 + fr] = f2bf(sc[tj][r] * inv[r]);
        }
        // ---- O = P V (within-wave LDS write->read; DS ops in-order per wave) ----
        #pragma unroll
        for (int td = 0; td < 2; td++) {
            f32x4 o = (f32x4){0.f, 0.f, 0.f, 0.f};
            #pragma unroll
            for (int kk = 0; kk < 4; kk++) {
                bf16x8 pa = *(const bf16x8*)&Pb[(wave * 16 + fr) * 132 + kk * 32 + fko];
                bf16x8 bv = *(const bf16x8*)&Vt[(td * 16 + fr) * 136 + kk * 32 + fko];
                o = __builtin_amdgcn_mfma_f32_16x16x32_bf16(pa, bv, o, 0, 0, 0);
            }
            #pragma unroll
            for (int r = 0; r < 4; r++) {
                const int i = half * 64 + wave * 16 + g * 4 + r;
                const int d = td * 16 + fr;
                out[((size_t)(bt * SSP + i)) * DMODEL + h * HD + d] = f2bf(o[r]);
            }
        }
    }
}

// ---------------- temporal attention: window of <=4 keys, per-thread scalar -----------
__device__ __forceinline__ float dot32(const float* __restrict__ qr,
                                       const unsigned short* __restrict__ Kt, int j)
{
    float a = 0.f;
    #pragma unroll
    for (int d = 0; d < 32; d++) a += qr[d] * bf2f(Kt[d * 128 + j]);
    return a;
}

__global__ __launch_bounds__(128)
void attn_temporal(const unsigned short* __restrict__ qkv,  // [NTOK][768]
                   unsigned short* __restrict__ out)        // [NTOK][256]
{
    __shared__ unsigned short Qt[32 * 128], Kt[32 * 128], Vt[32 * 128];  // transposed [d][t]
    const int bs = blockIdx.x, h = blockIdx.y;
    const int b = bs >> 7, sp = bs & 127;
    const int tid = threadIdx.x;   // t index 0..127
    const size_t rb = ((size_t)b * 16384 + (size_t)tid * 128 + sp) * 768 + (size_t)h * HD;
    #pragma unroll
    for (int c = 0; c < 4; c++) {
        bf16x8 q = *(const bf16x8*)(qkv + rb + c * 8);
        bf16x8 k = *(const bf16x8*)(qkv + rb + 256 + c * 8);
        bf16x8 v = *(const bf16x8*)(qkv + rb + 512 + c * 8);
        #pragma unroll
        for (int e = 0; e < 8; e++) {
            const int d = c * 8 + e;
            Qt[d * 128 + tid] = (unsigned short)q[e];
            Kt[d * 128 + tid] = (unsigned short)k[e];
            Vt[d * 128 + tid] = (unsigned short)v[e];
        }
    }
    __syncthreads();

    const int i = tid;
    float qr[32];
    #pragma unroll
    for (int d = 0; d < 32; d++) qr[d] = bf2f(Qt[d * 128 + i]);

    float s0 = -1e30f, s1 = -1e30f, s2 = -1e30f;
    if (i >= 3) s0 = dot32(qr, Kt, i - 3) * SCALE;
    if (i >= 2) s1 = dot32(qr, Kt, i - 2) * SCALE;
    if (i >= 1) s2 = dot32(qr, Kt, i - 1) * SCALE;
    const float s3 = dot32(qr, Kt, i) * SCALE;

    const float mx = fmaxf(fmaxf(s0, s1), fmaxf(s2, s3));
    const float p0 = __expf(s0 - mx), p1 = __expf(s1 - mx), p2 = __expf(s2 - mx), p3 = __expf(s3 - mx);
    const float inv = 1.0f / (p0 + p1 + p2 + p3);
    const int j0 = i >= 3 ? i - 3 : 0;
    const int j1 = i >= 2 ? i - 2 : 0;
    const int j2 = i >= 1 ? i - 1 : 0;
    const size_t ob = ((size_t)b * 16384 + (size_t)i * 128 + sp) * DMODEL + (size_t)h * HD;
    #pragma unroll
    for (int d = 0; d < 32; d++) {
        const float o = (p0 * bf2f(Vt[d * 128 + j0]) + p1 * bf2f(Vt[d * 128 + j1]) +
                         p2 * bf2f(Vt[d * 128 + j2]) + p3 * bf2f(Vt[d * 128 + i])) * inv;
        out[ob + d] = f2bf(o);
    }
}

// --------------------------------------------------------------------------------------
extern "C" void kernel_launch(void* const* d_in, const int* in_sizes, int n_in,
                              void* d_out, int out_size, void* d_ws, size_t ws_size,
                              hipStream_t stream)
{
    const int*   coords = (const int*)d_in[1];
    const float* Wqkv_s = (const float*)d_in[3];
    const float* bqkv_s = (const float*)d_in[4];
    const float* Wo_s   = (const float*)d_in[5];
    const float* bo_s   = (const float*)d_in[6];
    const float* Wqkv_t = (const float*)d_in[7];
    const float* bqkv_t = (const float*)d_in[8];
    const float* Wo_t   = (const float*)d_in[9];
    const float* bo_t   = (const float*)d_in[10];
    const float* g1     = (const float*)d_in[11];
    const float* g2     = (const float*)d_in[12];
    const float* g3     = (const float*)d_in[13];
    const float* W1     = (const float*)d_in[14];
    const float* b1     = (const float*)d_in[15];
    const float* W2     = (const float*)d_in[16];
    const float* b2     = (const float*)d_in[17];
    float* xo = (float*)d_out;

    char* ws = (char*)d_ws;
    unsigned short* wb  = (unsigned short*)ws;                                 // 2 MB weights
    unsigned short* xn  = (unsigned short*)(ws + (size_t)2 * 1024 * 1024);     // 32 MB norm / attn-out
    unsigned short* big = (unsigned short*)(ws + (size_t)34 * 1024 * 1024);    // 128 MB qkv / ffn-hidden

    unsigned short* wQKVs = wb;
    unsigned short* wOs   = wb + 196608;
    unsigned short* wQKVt = wb + 262144;
    unsigned short* wOt   = wb + 458752;
    unsigned short* w1b   = wb + 524288;
    unsigned short* w2b   = wb + 786432;

    // x residual lives in d_out (fp32), updated in place by EPI==2 GEMMs
    (void)hipMemcpyAsync(d_out, d_in[0], (size_t)NTOK * DMODEL * sizeof(float),
                         hipMemcpyDeviceToDevice, stream);
    cvt_w<<<4096, 256, 0, stream>>>(Wqkv_s, Wo_s, Wqkv_t, Wo_t, W1, W2, wb);

    // ---- spatial block ----
    rmsnorm_k<<<NTOK, 256, 0, stream>>>(xo, g1, xn);
    gemm_bt<0><<<dim3(512, 6), 256, 0, stream>>>(xn, wQKVs, bqkv_s, big, nullptr, NTOK, 768, 256);
    attn_spatial<<<dim3(512, 8), 256, 0, stream>>>(big, coords, xn);
    gemm_bt<2><<<dim3(512, 2), 256, 0, stream>>>(xn, wOs, bo_s, nullptr, xo, NTOK, 256, 256);

    // ---- temporal block ----
    rmsnorm_k<<<NTOK, 256, 0, stream>>>(xo, g2, xn);
    gemm_bt<0><<<dim3(512, 6), 256, 0, stream>>>(xn, wQKVt, bqkv_t, big, nullptr, NTOK, 768, 256);
    attn_temporal<<<dim3(512, 8), 128, 0, stream>>>(big, xn);
    gemm_bt<2><<<dim3(512, 2), 256, 0, stream>>>(xn, wOt, bo_t, nullptr, xo, NTOK, 256, 256);

    // ---- FFN block ----
    rmsnorm_k<<<NTOK, 256, 0, stream>>>(xo, g3, xn);
    gemm_bt<1><<<dim3(512, 8), 256, 0, stream>>>(xn, w1b, b1, big, nullptr, NTOK, 1024, 256);
    gemm_bt<2><<<dim3(512, 2), 256, 0, stream>>>(big, w2b, b2, nullptr, xo, NTOK, 256, 1024);
}

// Round 4
// 642.599 us; speedup vs baseline: 1.4642x; 1.1655x over previous
//
#include <hip/hip_runtime.h>
#include <hip/hip_bf16.h>

typedef __attribute__((ext_vector_type(4))) float f32x4;
typedef __attribute__((ext_vector_type(8))) short bf16x8;
typedef __attribute__((ext_vector_type(4))) unsigned short u16x4;

#define NTOK 65536
#define DMODEL 256
#define DFF 1024
#define NH 8
#define HD 32
#define SSP 128
#define TLEN 128
#define SCALE 0.17677669529663687f  /* 1/sqrt(32) */

__device__ __forceinline__ float bf2f(unsigned short u) {
    return __builtin_bit_cast(float, (unsigned int)u << 16);
}
__device__ __forceinline__ unsigned short f2bf(float f) {
    unsigned int u = __builtin_bit_cast(unsigned int, f);
    unsigned int r = u + 0x7fffu + ((u >> 16) & 1u);
    return (unsigned short)(r >> 16);
}
__device__ __forceinline__ void gload_lds16(const void* g, void* l) {
    __builtin_amdgcn_global_load_lds((const __attribute__((address_space(1))) void*)g,
                                     (__attribute__((address_space(3))) void*)l, 16, 0, 0);
}

// ---------------- weight fp32 -> bf16 conversion (all 6 mats, 1,048,576 elems) --------
__global__ __launch_bounds__(256)
void cvt_w(const float* __restrict__ a, const float* __restrict__ b,
           const float* __restrict__ c, const float* __restrict__ d,
           const float* __restrict__ e, const float* __restrict__ f,
           unsigned short* __restrict__ o)
{
    int i = blockIdx.x * 256 + threadIdx.x;
    float v;
    if      (i < 196608)  v = a[i];
    else if (i < 262144)  v = b[i - 196608];
    else if (i < 458752)  v = c[i - 262144];
    else if (i < 524288)  v = d[i - 458752];
    else if (i < 786432)  v = e[i - 524288];
    else                  v = f[i - 786432];
    o[i] = f2bf(v);
}

// ---------------- RMSNorm: one wave per row, no barriers ------------------------------
__global__ __launch_bounds__(256)
void rmsnorm_k(const float* __restrict__ x, const float* __restrict__ g,
               unsigned short* __restrict__ out)
{
    const int row = blockIdx.x * 4 + (threadIdx.x >> 6);
    const int lane = threadIdx.x & 63;
    const float4 v = *(const float4*)&x[(size_t)row * DMODEL + lane * 4];
    float s = v.x * v.x + v.y * v.y + v.z * v.z + v.w * v.w;
    #pragma unroll
    for (int o = 1; o < 64; o <<= 1) s += __shfl_xor(s, o);
    const float rinv = rsqrtf(s * (1.0f / DMODEL) + 1.1920929e-7f);
    const float4 gv = *(const float4*)&g[lane * 4];
    u16x4 o4;
    o4[0] = f2bf(v.x * rinv * gv.x);
    o4[1] = f2bf(v.y * rinv * gv.y);
    o4[2] = f2bf(v.z * rinv * gv.z);
    o4[3] = f2bf(v.w * rinv * gv.w);
    *(u16x4*)&out[(size_t)row * DMODEL + lane * 4] = o4;
}

// ---------------- GEMM: C[M,N] = A[M,K] * W[N,K]^T + bias (both bf16 row-major) -------
// BK=64, XOR-swizzled LDS (16B chunk ^= (row&7)) applied to gload_lds SOURCE and ds_read.
// 1D grid, XCD-bijective swizzle; col-tile fastest => A row-panel reused across col-tiles.
// EPI 0: bias -> bf16 out; EPI 1: bias+GELU -> bf16 out; EPI 2: bias + fp32 residual +=
template<int EPI>
__global__ __launch_bounds__(256)
void gemm_bt(const unsigned short* __restrict__ A,
             const unsigned short* __restrict__ W,
             const float* __restrict__ bias,
             unsigned short* __restrict__ Cb,
             float* __restrict__ Cf,
             int N, int K, int NCT)
{
    __shared__ unsigned short lds[17408];    // 34816 B: staging 32KB, epilogue [128][136]
    unsigned short* As = lds;                // [128][64]
    unsigned short* Bs = lds + 8192;         // [128][64]

    const int tid = threadIdx.x;
    const int wave = tid >> 6, lane = tid & 63;
    const int wr = wave >> 1, wc = wave & 1;

    const int nwg = gridDim.x;
    const int bid = blockIdx.x;
    const int lin = (bid & 7) * (nwg >> 3) + (bid >> 3);   // nwg % 8 == 0 for all launches
    const int row0 = (lin / NCT) * 128;
    const int col0 = (lin % NCT) * 128;

    f32x4 acc[4][4];
    #pragma unroll
    for (int i = 0; i < 4; i++)
        #pragma unroll
        for (int j = 0; j < 4; j++)
            acc[i][j] = (f32x4){0.f, 0.f, 0.f, 0.f};

    const int srow  = tid >> 3;                       // 0..31
    const int kx    = ((tid & 7) * 8) ^ ((srow & 7) * 8);  // swizzled source k-elem

    const int fr = lane & 15, g = lane >> 4;
    const int sw = (fr & 7) * 8;                      // read-side XOR (row&7 == fr&7)

    for (int k0 = 0; k0 < K; k0 += 64) {
        #pragma unroll
        for (int q = 0; q < 4; q++) {
            const int row = q * 32 + srow;
            gload_lds16(A + (size_t)(row0 + row) * K + k0 + kx, As + q * 2048 + tid * 8);
            gload_lds16(W + (size_t)(col0 + row) * K + k0 + kx, Bs + q * 2048 + tid * 8);
        }
        __syncthreads();
        #pragma unroll
        for (int kh = 0; kh < 2; kh++) {
            const int ke = (kh * 32 + g * 8) ^ sw;
            bf16x8 af[4], bw[4];
            #pragma unroll
            for (int i = 0; i < 4; i++)
                af[i] = *(const bf16x8*)&As[(wr * 64 + i * 16 + fr) * 64 + ke];
            #pragma unroll
            for (int j = 0; j < 4; j++)
                bw[j] = *(const bf16x8*)&Bs[(wc * 64 + j * 16 + fr) * 64 + ke];
            #pragma unroll
            for (int i = 0; i < 4; i++)
                #pragma unroll
                for (int j = 0; j < 4; j++)
                    acc[i][j] = __builtin_amdgcn_mfma_f32_16x16x32_bf16(af[i], bw[j], acc[i][j], 0, 0, 0);
        }
        __syncthreads();
    }

    if constexpr (EPI == 2) {
        #pragma unroll
        for (int i = 0; i < 4; i++) {
            #pragma unroll
            for (int j = 0; j < 4; j++) {
                const int col = col0 + wc * 64 + j * 16 + fr;
                const float bv = bias[col];
                #pragma unroll
                for (int r = 0; r < 4; r++) {
                    const int row = row0 + wr * 64 + i * 16 + g * 4 + r;
                    Cf[(size_t)row * N + col] += acc[i][j][r] + bv;
                }
            }
        }
    } else {
        // stage C tile bf16 in LDS ([128][136], 16B-aligned rows), then coalesced stores
        #pragma unroll
        for (int i = 0; i < 4; i++) {
            #pragma unroll
            for (int j = 0; j < 4; j++) {
                const int col = wc * 64 + j * 16 + fr;
                const float bv = bias[col0 + col];
                #pragma unroll
                for (int r = 0; r < 4; r++) {
                    float v = acc[i][j][r] + bv;
                    if constexpr (EPI == 1) v = 0.5f * v * (1.0f + erff(v * 0.70710678118654752f));
                    lds[(wr * 64 + i * 16 + g * 4 + r) * 136 + col] = f2bf(v);
                }
            }
        }
        __syncthreads();
        #pragma unroll
        for (int q = 0; q < 8; q++) {
            const int chunk = q * 256 + tid;
            const int row = chunk >> 4, c16 = chunk & 15;
            *(bf16x8*)&Cb[(size_t)(row0 + row) * N + col0 + c16 * 8] =
                *(const bf16x8*)&lds[row * 136 + c16 * 8];
        }
    }
}

// ---------------- spatial attention: one block per (bt, head), 128x128, MFMA ----------
__global__ __launch_bounds__(256)
void attn_spatial(const unsigned short* __restrict__ qkv,  // [NTOK][768]
                  const int* __restrict__ coords,          // [128][2]
                  unsigned short* __restrict__ out)        // [NTOK][256]
{
    __shared__ unsigned short Qs[128 * 32];
    __shared__ unsigned short Ks[128 * 32];
    __shared__ unsigned short Vt[32 * 136];   // V^T, padded rows
    __shared__ unsigned short Pb[64 * 132];   // bf16 P for one 64-row half
    __shared__ int cx[128], cy[128];

    const int bt = blockIdx.x, h = blockIdx.y;
    const int tid = threadIdx.x, wave = tid >> 6, lane = tid & 63;
    const size_t base = (size_t)bt * SSP * 768 + (size_t)h * HD;

    {   // stage Q,K (row-major [128][32]) and V transposed
        const int rr = tid >> 1, cb = (tid & 1) * 16;
        const unsigned short* p = qkv + base + (size_t)rr * 768 + cb;
        *(bf16x8*)&Qs[rr * 32 + cb]     = *(const bf16x8*)p;
        *(bf16x8*)&Qs[rr * 32 + cb + 8] = *(const bf16x8*)(p + 8);
        p += 256;
        *(bf16x8*)&Ks[rr * 32 + cb]     = *(const bf16x8*)p;
        *(bf16x8*)&Ks[rr * 32 + cb + 8] = *(const bf16x8*)(p + 8);
        p += 256;
        bf16x8 v0 = *(const bf16x8*)p, v1 = *(const bf16x8*)(p + 8);
        #pragma unroll
        for (int e = 0; e < 8; e++) {
            Vt[(cb + e) * 136 + rr]     = (unsigned short)v0[e];
            Vt[(cb + 8 + e) * 136 + rr] = (unsigned short)v1[e];
        }
        if (tid < 128) { cx[tid] = coords[2 * tid]; cy[tid] = coords[2 * tid + 1]; }
    }
    __syncthreads();

    const int fr = lane & 15;        // A-frag row / C-col within tile
    const int g  = lane >> 4;        // 16-lane group
    const int fko = g * 8;           // k offset within 32

    for (int half = 0; half < 2; half++) {
        const int rbase = half * 64 + wave * 16;   // this wave's 16 q-rows
        bf16x8 aq = *(const bf16x8*)&Qs[(rbase + fr) * 32 + fko];
        f32x4 sc[8];
        #pragma unroll
        for (int tj = 0; tj < 8; tj++) {
            bf16x8 bk = *(const bf16x8*)&Ks[(tj * 16 + fr) * 32 + fko];
            sc[tj] = __builtin_amdgcn_mfma_f32_16x16x32_bf16(aq, bk, (f32x4){0.f,0.f,0.f,0.f}, 0, 0, 0);
        }
        int cxi[4], cyi[4];
        #pragma unroll
        for (int r = 0; r < 4; r++) { const int i = rbase + g * 4 + r; cxi[r] = cx[i]; cyi[r] = cy[i]; }
        float m[4] = {-1e30f, -1e30f, -1e30f, -1e30f};
        #pragma unroll
        for (int tj = 0; tj < 8; tj++) {
            const int j = tj * 16 + fr;
            const int cxj = cx[j], cyj = cy[j];
            #pragma unroll
            for (int r = 0; r < 4; r++) {
                int dx = cxi[r] - cxj; dx = dx < 0 ? -dx : dx;
                int dy = cyi[r] - cyj; dy = dy < 0 ? -dy : dy;
                const float v = ((dx > dy ? dx : dy) > 4) ? -1e9f : sc[tj][r] * SCALE;
                sc[tj][r] = v;
                m[r] = fmaxf(m[r], v);
            }
        }
        #pragma unroll
        for (int r = 0; r < 4; r++) {
            #pragma unroll
            for (int o = 1; o < 16; o <<= 1) m[r] = fmaxf(m[r], __shfl_xor(m[r], o));
        }
        float sm[4] = {0.f, 0.f, 0.f, 0.f};
        #pragma unroll
        for (int tj = 0; tj < 8; tj++) {
            #pragma unroll
            for (int r = 0; r < 4; r++) {
                const float e = __expf(sc[tj][r] - m[r]);
                sc[tj][r] = e;
                sm[r] += e;
            }
        }
        #pragma unroll
        for (int r = 0; r < 4; r++) {
            #pragma unroll
            for (int o = 1; o < 16; o <<= 1) sm[r] += __shfl_xor(sm[r], o);
        }
        float inv[4];
        #pragma unroll
        for (int r = 0; r < 4; r++) inv[r] = 1.0f / sm[r];
        #pragma unroll
        for (int tj = 0; tj < 8; tj++) {
            #pragma unroll
            for (int r = 0; r < 4; r++)
                Pb[(wave * 16 + g * 4 + r) * 132 + tj * 16 + fr] = f2bf(sc[tj][r] * inv[r]);
        }
        #pragma unroll
        for (int td = 0; td < 2; td++) {
            f32x4 o = (f32x4){0.f, 0.f, 0.f, 0.f};
            #pragma unroll
            for (int kk = 0; kk < 4; kk++) {
                bf16x8 pa = *(const bf16x8*)&Pb[(wave * 16 + fr) * 132 + kk * 32 + fko];
                bf16x8 bv = *(const bf16x8*)&Vt[(td * 16 + fr) * 136 + kk * 32 + fko];
                o = __builtin_amdgcn_mfma_f32_16x16x32_bf16(pa, bv, o, 0, 0, 0);
            }
            #pragma unroll
            for (int r = 0; r < 4; r++) {
                const int i = half * 64 + wave * 16 + g * 4 + r;
                const int d = td * 16 + fr;
                out[((size_t)(bt * SSP + i)) * DMODEL + h * HD + d] = f2bf(o[r]);
            }
        }
    }
}

// ---------------- temporal attention: window of <=4 keys, per-thread scalar -----------
__device__ __forceinline__ float dot32(const float* __restrict__ qr,
                                       const unsigned short* __restrict__ Kt, int j)
{
    float a = 0.f;
    #pragma unroll
    for (int d = 0; d < 32; d++) a += qr[d] * bf2f(Kt[d * 128 + j]);
    return a;
}

__global__ __launch_bounds__(128)
void attn_temporal(const unsigned short* __restrict__ qkv,  // [NTOK][768]
                   unsigned short* __restrict__ out)        // [NTOK][256]
{
    __shared__ unsigned short Qt[32 * 128], Kt[32 * 128], Vt[32 * 128];  // transposed [d][t]
    const int bs = blockIdx.x, h = blockIdx.y;
    const int b = bs >> 7, sp = bs & 127;
    const int tid = threadIdx.x;   // t index 0..127
    const size_t rb = ((size_t)b * 16384 + (size_t)tid * 128 + sp) * 768 + (size_t)h * HD;
    #pragma unroll
    for (int c = 0; c < 4; c++) {
        bf16x8 q = *(const bf16x8*)(qkv + rb + c * 8);
        bf16x8 k = *(const bf16x8*)(qkv + rb + 256 + c * 8);
        bf16x8 v = *(const bf16x8*)(qkv + rb + 512 + c * 8);
        #pragma unroll
        for (int e = 0; e < 8; e++) {
            const int d = c * 8 + e;
            Qt[d * 128 + tid] = (unsigned short)q[e];
            Kt[d * 128 + tid] = (unsigned short)k[e];
            Vt[d * 128 + tid] = (unsigned short)v[e];
        }
    }
    __syncthreads();

    const int i = tid;
    float qr[32];
    #pragma unroll
    for (int d = 0; d < 32; d++) qr[d] = bf2f(Qt[d * 128 + i]);

    float s0 = -1e30f, s1 = -1e30f, s2 = -1e30f;
    if (i >= 3) s0 = dot32(qr, Kt, i - 3) * SCALE;
    if (i >= 2) s1 = dot32(qr, Kt, i - 2) * SCALE;
    if (i >= 1) s2 = dot32(qr, Kt, i - 1) * SCALE;
    const float s3 = dot32(qr, Kt, i) * SCALE;

    const float mx = fmaxf(fmaxf(s0, s1), fmaxf(s2, s3));
    const float p0 = __expf(s0 - mx), p1 = __expf(s1 - mx), p2 = __expf(s2 - mx), p3 = __expf(s3 - mx);
    const float inv = 1.0f / (p0 + p1 + p2 + p3);
    const int j0 = i >= 3 ? i - 3 : 0;
    const int j1 = i >= 2 ? i - 2 : 0;
    const int j2 = i >= 1 ? i - 1 : 0;
    const size_t ob = ((size_t)b * 16384 + (size_t)i * 128 + sp) * DMODEL + (size_t)h * HD;
    #pragma unroll
    for (int d = 0; d < 32; d++) {
        const float o = (p0 * bf2f(Vt[d * 128 + j0]) + p1 * bf2f(Vt[d * 128 + j1]) +
                         p2 * bf2f(Vt[d * 128 + j2]) + p3 * bf2f(Vt[d * 128 + i])) * inv;
        out[ob + d] = f2bf(o);
    }
}

// --------------------------------------------------------------------------------------
extern "C" void kernel_launch(void* const* d_in, const int* in_sizes, int n_in,
                              void* d_out, int out_size, void* d_ws, size_t ws_size,
                              hipStream_t stream)
{
    const int*   coords = (const int*)d_in[1];
    const float* Wqkv_s = (const float*)d_in[3];
    const float* bqkv_s = (const float*)d_in[4];
    const float* Wo_s   = (const float*)d_in[5];
    const float* bo_s   = (const float*)d_in[6];
    const float* Wqkv_t = (const float*)d_in[7];
    const float* bqkv_t = (const float*)d_in[8];
    const float* Wo_t   = (const float*)d_in[9];
    const float* bo_t   = (const float*)d_in[10];
    const float* g1     = (const float*)d_in[11];
    const float* g2     = (const float*)d_in[12];
    const float* g3     = (const float*)d_in[13];
    const float* W1     = (const float*)d_in[14];
    const float* b1     = (const float*)d_in[15];
    const float* W2     = (const float*)d_in[16];
    const float* b2     = (const float*)d_in[17];
    float* xo = (float*)d_out;

    char* ws = (char*)d_ws;
    unsigned short* wb  = (unsigned short*)ws;                                 // 2 MB weights
    unsigned short* xn  = (unsigned short*)(ws + (size_t)2 * 1024 * 1024);     // 32 MB norm / attn-out
    unsigned short* big = (unsigned short*)(ws + (size_t)34 * 1024 * 1024);    // 128 MB qkv / ffn-hidden

    unsigned short* wQKVs = wb;
    unsigned short* wOs   = wb + 196608;
    unsigned short* wQKVt = wb + 262144;
    unsigned short* wOt   = wb + 458752;
    unsigned short* w1b   = wb + 524288;
    unsigned short* w2b   = wb + 786432;

    // x residual lives in d_out (fp32), updated in place by EPI==2 GEMMs
    (void)hipMemcpyAsync(d_out, d_in[0], (size_t)NTOK * DMODEL * sizeof(float),
                         hipMemcpyDeviceToDevice, stream);
    cvt_w<<<4096, 256, 0, stream>>>(Wqkv_s, Wo_s, Wqkv_t, Wo_t, W1, W2, wb);

    // ---- spatial block ----
    rmsnorm_k<<<16384, 256, 0, stream>>>(xo, g1, xn);
    gemm_bt<0><<<3072, 256, 0, stream>>>(xn, wQKVs, bqkv_s, big, nullptr, 768, 256, 6);
    attn_spatial<<<dim3(512, 8), 256, 0, stream>>>(big, coords, xn);
    gemm_bt<2><<<1024, 256, 0, stream>>>(xn, wOs, bo_s, nullptr, xo, 256, 256, 2);

    // ---- temporal block ----
    rmsnorm_k<<<16384, 256, 0, stream>>>(xo, g2, xn);
    gemm_bt<0><<<3072, 256, 0, stream>>>(xn, wQKVt, bqkv_t, big, nullptr, 768, 256, 6);
    attn_temporal<<<dim3(512, 8), 128, 0, stream>>>(big, xn);
    gemm_bt<2><<<1024, 256, 0, stream>>>(xn, wOt, bo_t, nullptr, xo, 256, 256, 2);

    // ---- FFN block ----
    rmsnorm_k<<<16384, 256, 0, stream>>>(xo, g3, xn);
    gemm_bt<1><<<4096, 256, 0, stream>>>(xn, w1b, b1, big, nullptr, 1024, 256, 8);
    gemm_bt<2><<<1024, 256, 0, stream>>>(big, w2b, b2, nullptr, xo, 256, 1024, 2);
}

// Round 5
// 641.054 us; speedup vs baseline: 1.4677x; 1.0024x over previous
//
#include <hip/hip_runtime.h>
#include <hip/hip_bf16.h>

typedef __attribute__((ext_vector_type(4))) float f32x4;
typedef __attribute__((ext_vector_type(8))) short bf16x8;
typedef __attribute__((ext_vector_type(4))) unsigned short u16x4;

#define NTOK 65536
#define DMODEL 256
#define DFF 1024
#define NH 8
#define HD 32
#define SSP 128
#define TLEN 128
#define SCALE 0.17677669529663687f  /* 1/sqrt(32) */

__device__ __forceinline__ float bf2f(unsigned short u) {
    return __builtin_bit_cast(float, (unsigned int)u << 16);
}
__device__ __forceinline__ unsigned short f2bf(float f) {
    unsigned int u = __builtin_bit_cast(unsigned int, f);
    unsigned int r = u + 0x7fffu + ((u >> 16) & 1u);
    return (unsigned short)(r >> 16);
}
__device__ __forceinline__ void gload_lds16(const void* g, void* l) {
    __builtin_amdgcn_global_load_lds((const __attribute__((address_space(1))) void*)g,
                                     (__attribute__((address_space(3))) void*)l, 16, 0, 0);
}

// ---------------- weight fp32 -> bf16 conversion (all 6 mats, 1,048,576 elems) --------
__global__ __launch_bounds__(256)
void cvt_w(const float* __restrict__ a, const float* __restrict__ b,
           const float* __restrict__ c, const float* __restrict__ d,
           const float* __restrict__ e, const float* __restrict__ f,
           unsigned short* __restrict__ o)
{
    int i = blockIdx.x * 256 + threadIdx.x;
    float v;
    if      (i < 196608)  v = a[i];
    else if (i < 262144)  v = b[i - 196608];
    else if (i < 458752)  v = c[i - 262144];
    else if (i < 524288)  v = d[i - 458752];
    else if (i < 786432)  v = e[i - 524288];
    else                  v = f[i - 786432];
    o[i] = f2bf(v);
}

// ---------------- copy x -> residual (fp32) + rmsnorm -> bf16, one wave per row -------
__global__ __launch_bounds__(256)
void rms_copy(const float* __restrict__ x, const float* __restrict__ g,
              float* __restrict__ xo, unsigned short* __restrict__ xn)
{
    const int row = blockIdx.x * 4 + (threadIdx.x >> 6);
    const int lane = threadIdx.x & 63;
    const float4 v = *(const float4*)&x[(size_t)row * DMODEL + lane * 4];
    float s = v.x * v.x + v.y * v.y + v.z * v.z + v.w * v.w;
    #pragma unroll
    for (int o = 1; o < 64; o <<= 1) s += __shfl_xor(s, o);
    const float rinv = rsqrtf(s * (1.0f / DMODEL) + 1.1920929e-7f);
    *(float4*)&xo[(size_t)row * DMODEL + lane * 4] = v;
    const float4 gv = *(const float4*)&g[lane * 4];
    u16x4 o4;
    o4[0] = f2bf(v.x * rinv * gv.x);
    o4[1] = f2bf(v.y * rinv * gv.y);
    o4[2] = f2bf(v.z * rinv * gv.z);
    o4[3] = f2bf(v.w * rinv * gv.w);
    *(u16x4*)&xn[(size_t)row * DMODEL + lane * 4] = o4;
}

// ---------------- GEMM: C[M,N] = A[M,K] * W[N,K]^T + bias (both bf16 row-major) -------
// BK=64, XOR-swizzled LDS; 1D grid, XCD-bijective swizzle, col-tile fastest.
// EPI 0: bias -> bf16 out; EPI 1: bias+GELU(tanh approx) -> bf16 out; EPI 2: fp32 residual +=
template<int EPI>
__global__ __launch_bounds__(256)
void gemm_bt(const unsigned short* __restrict__ A,
             const unsigned short* __restrict__ W,
             const float* __restrict__ bias,
             unsigned short* __restrict__ Cb,
             float* __restrict__ Cf,
             int N, int K, int NCT)
{
    __shared__ unsigned short lds[17408];    // staging 32KB; epilogue reuse [128][136]
    unsigned short* As = lds;                // [128][64]
    unsigned short* Bs = lds + 8192;         // [128][64]

    const int tid = threadIdx.x;
    const int wave = tid >> 6, lane = tid & 63;
    const int wr = wave >> 1, wc = wave & 1;

    const int nwg = gridDim.x;
    const int bid = blockIdx.x;
    const int lin = (bid & 7) * (nwg >> 3) + (bid >> 3);   // nwg % 8 == 0
    const int row0 = (lin / NCT) * 128;
    const int col0 = (lin % NCT) * 128;

    f32x4 acc[4][4];
    #pragma unroll
    for (int i = 0; i < 4; i++)
        #pragma unroll
        for (int j = 0; j < 4; j++)
            acc[i][j] = (f32x4){0.f, 0.f, 0.f, 0.f};

    const int srow  = tid >> 3;                            // 0..31
    const int kx    = ((tid & 7) * 8) ^ ((srow & 7) * 8);  // swizzled source k-elem

    const int fr = lane & 15, g = lane >> 4;
    const int sw = (fr & 7) * 8;                           // read-side XOR

    for (int k0 = 0; k0 < K; k0 += 64) {
        #pragma unroll
        for (int q = 0; q < 4; q++) {
            const int row = q * 32 + srow;
            gload_lds16(A + (size_t)(row0 + row) * K + k0 + kx, As + q * 2048 + tid * 8);
            gload_lds16(W + (size_t)(col0 + row) * K + k0 + kx, Bs + q * 2048 + tid * 8);
        }
        __syncthreads();
        #pragma unroll
        for (int kh = 0; kh < 2; kh++) {
            const int ke = (kh * 32 + g * 8) ^ sw;
            bf16x8 af[4], bw[4];
            #pragma unroll
            for (int i = 0; i < 4; i++)
                af[i] = *(const bf16x8*)&As[(wr * 64 + i * 16 + fr) * 64 + ke];
            #pragma unroll
            for (int j = 0; j < 4; j++)
                bw[j] = *(const bf16x8*)&Bs[(wc * 64 + j * 16 + fr) * 64 + ke];
            #pragma unroll
            for (int i = 0; i < 4; i++)
                #pragma unroll
                for (int j = 0; j < 4; j++)
                    acc[i][j] = __builtin_amdgcn_mfma_f32_16x16x32_bf16(af[i], bw[j], acc[i][j], 0, 0, 0);
        }
        __syncthreads();
    }

    if constexpr (EPI == 2) {
        #pragma unroll
        for (int i = 0; i < 4; i++) {
            #pragma unroll
            for (int j = 0; j < 4; j++) {
                const int col = col0 + wc * 64 + j * 16 + fr;
                const float bv = bias[col];
                #pragma unroll
                for (int r = 0; r < 4; r++) {
                    const int row = row0 + wr * 64 + i * 16 + g * 4 + r;
                    Cf[(size_t)row * N + col] += acc[i][j][r] + bv;
                }
            }
        }
    } else {
        #pragma unroll
        for (int i = 0; i < 4; i++) {
            #pragma unroll
            for (int j = 0; j < 4; j++) {
                const int col = wc * 64 + j * 16 + fr;
                const float bv = bias[col0 + col];
                #pragma unroll
                for (int r = 0; r < 4; r++) {
                    float v = acc[i][j][r] + bv;
                    if constexpr (EPI == 1) {
                        // GELU tanh approx: v * sigmoid(1.5958*(v + 0.044715 v^3))
                        const float y = 1.5957691216057308f * (v + 0.044715f * v * v * v);
                        v = v / (1.0f + __expf(-y));
                    }
                    lds[(wr * 64 + i * 16 + g * 4 + r) * 136 + col] = f2bf(v);
                }
            }
        }
        __syncthreads();
        #pragma unroll
        for (int q = 0; q < 8; q++) {
            const int chunk = q * 256 + tid;
            const int row = chunk >> 4, c16 = chunk & 15;
            *(bf16x8*)&Cb[(size_t)(row0 + row) * N + col0 + c16 * 8] =
                *(const bf16x8*)&lds[row * 136 + c16 * 8];
        }
    }
}

// ---------------- fused GEMM + residual += + rmsnorm (full-row tile 64x256) -----------
// xo[row] += A*W^T + bias; xn[row] = rmsnorm(xo[row]) * g   (in-place-safe per block)
__global__ __launch_bounds__(256)
void gemm_rms(const unsigned short* __restrict__ A,
              const unsigned short* __restrict__ W,
              const float* __restrict__ bias,
              float* __restrict__ xo,
              const float* __restrict__ gv,
              unsigned short* __restrict__ xn,
              int K)
{
    __shared__ unsigned short As[64 * 64];    // 8 KB
    __shared__ unsigned short Bs[256 * 64];   // 32 KB
    __shared__ float red[64 * 4];             // per-row per-wave partial sums

    const int tid = threadIdx.x;
    const int wave = tid >> 6, lane = tid & 63;
    const int fr = lane & 15, g4 = lane >> 4;

    const int nwg = gridDim.x;
    const int bid = blockIdx.x;
    const int lin = (bid & 7) * (nwg >> 3) + (bid >> 3);
    const int row0 = lin * 64;

    f32x4 acc[4][4];
    #pragma unroll
    for (int i = 0; i < 4; i++)
        #pragma unroll
        for (int j = 0; j < 4; j++)
            acc[i][j] = (f32x4){0.f, 0.f, 0.f, 0.f};

    const int srow = tid >> 3;
    const int kx   = ((tid & 7) * 8) ^ ((srow & 7) * 8);
    const int sw   = (fr & 7) * 8;

    for (int k0 = 0; k0 < K; k0 += 64) {
        #pragma unroll
        for (int p = 0; p < 2; p++)
            gload_lds16(A + (size_t)(row0 + p * 32 + srow) * K + k0 + kx, As + p * 2048 + tid * 8);
        #pragma unroll
        for (int p = 0; p < 8; p++)
            gload_lds16(W + (size_t)(p * 32 + srow) * K + k0 + kx, Bs + p * 2048 + tid * 8);
        __syncthreads();
        #pragma unroll
        for (int kh = 0; kh < 2; kh++) {
            const int ke = (kh * 32 + g4 * 8) ^ sw;
            bf16x8 af[4], bw[4];
            #pragma unroll
            for (int i = 0; i < 4; i++)
                af[i] = *(const bf16x8*)&As[(i * 16 + fr) * 64 + ke];
            #pragma unroll
            for (int j = 0; j < 4; j++)
                bw[j] = *(const bf16x8*)&Bs[(wave * 64 + j * 16 + fr) * 64 + ke];
            #pragma unroll
            for (int i = 0; i < 4; i++)
                #pragma unroll
                for (int j = 0; j < 4; j++)
                    acc[i][j] = __builtin_amdgcn_mfma_f32_16x16x32_bf16(af[i], bw[j], acc[i][j], 0, 0, 0);
        }
        __syncthreads();
    }

    // epilogue: xnew = xo + acc + bias; write xo; row sum-of-squares -> rinv -> write xn
    #pragma unroll
    for (int i = 0; i < 4; i++) {
        #pragma unroll
        for (int j = 0; j < 4; j++) {
            const int col = wave * 64 + j * 16 + fr;
            const float bv = bias[col];
            #pragma unroll
            for (int r = 0; r < 4; r++) {
                const int row = row0 + i * 16 + g4 * 4 + r;
                const float xv = xo[(size_t)row * DMODEL + col] + acc[i][j][r] + bv;
                xo[(size_t)row * DMODEL + col] = xv;
                acc[i][j][r] = xv;
            }
        }
    }
    #pragma unroll
    for (int i = 0; i < 4; i++) {
        #pragma unroll
        for (int r = 0; r < 4; r++) {
            float p = acc[i][0][r] * acc[i][0][r] + acc[i][1][r] * acc[i][1][r]
                    + acc[i][2][r] * acc[i][2][r] + acc[i][3][r] * acc[i][3][r];
            #pragma unroll
            for (int o = 1; o < 16; o <<= 1) p += __shfl_xor(p, o);
            if (fr == 0) red[(i * 16 + g4 * 4 + r) * 4 + wave] = p;
        }
    }
    __syncthreads();
    #pragma unroll
    for (int i = 0; i < 4; i++) {
        #pragma unroll
        for (int r = 0; r < 4; r++) {
            const int rl = i * 16 + g4 * 4 + r;
            const float rsq = red[rl * 4 + 0] + red[rl * 4 + 1] + red[rl * 4 + 2] + red[rl * 4 + 3];
            const float rinv = rsqrtf(rsq * (1.0f / DMODEL) + 1.1920929e-7f);
            #pragma unroll
            for (int j = 0; j < 4; j++) {
                const int col = wave * 64 + j * 16 + fr;
                xn[(size_t)(row0 + rl) * DMODEL + col] = f2bf(acc[i][j][r] * rinv * gv[col]);
            }
        }
    }
}

// ---------------- spatial attention: one block per (bt, head), 128x128, MFMA ----------
__global__ __launch_bounds__(256)
void attn_spatial(const unsigned short* __restrict__ qkv,  // [NTOK][768]
                  const int* __restrict__ coords,          // [128][2]
                  unsigned short* __restrict__ out)        // [NTOK][256]
{
    __shared__ unsigned short Qs[128 * 32];
    __shared__ unsigned short Ks[128 * 32];
    __shared__ unsigned short Vt[32 * 136];   // V^T, padded rows
    __shared__ unsigned short Pb[64 * 132];   // bf16 P for one 64-row half
    __shared__ int cx[128], cy[128];

    const int bt = blockIdx.x, h = blockIdx.y;
    const int tid = threadIdx.x, wave = tid >> 6, lane = tid & 63;
    const size_t base = (size_t)bt * SSP * 768 + (size_t)h * HD;

    {   // stage Q,K (row-major [128][32]) and V transposed
        const int rr = tid >> 1, cb = (tid & 1) * 16;
        const unsigned short* p = qkv + base + (size_t)rr * 768 + cb;
        *(bf16x8*)&Qs[rr * 32 + cb]     = *(const bf16x8*)p;
        *(bf16x8*)&Qs[rr * 32 + cb + 8] = *(const bf16x8*)(p + 8);
        p += 256;
        *(bf16x8*)&Ks[rr * 32 + cb]     = *(const bf16x8*)p;
        *(bf16x8*)&Ks[rr * 32 + cb + 8] = *(const bf16x8*)(p + 8);
        p += 256;
        bf16x8 v0 = *(const bf16x8*)p, v1 = *(const bf16x8*)(p + 8);
        #pragma unroll
        for (int e = 0; e < 8; e++) {
            Vt[(cb + e) * 136 + rr]     = (unsigned short)v0[e];
            Vt[(cb + 8 + e) * 136 + rr] = (unsigned short)v1[e];
        }
        if (tid < 128) { cx[tid] = coords[2 * tid]; cy[tid] = coords[2 * tid + 1]; }
    }
    __syncthreads();

    const int fr = lane & 15;
    const int g  = lane >> 4;
    const int fko = g * 8;

    for (int half = 0; half < 2; half++) {
        const int rbase = half * 64 + wave * 16;
        bf16x8 aq = *(const bf16x8*)&Qs[(rbase + fr) * 32 + fko];
        f32x4 sc[8];
        #pragma unroll
        for (int tj = 0; tj < 8; tj++) {
            bf16x8 bk = *(const bf16x8*)&Ks[(tj * 16 + fr) * 32 + fko];
            sc[tj] = __builtin_amdgcn_mfma_f32_16x16x32_bf16(aq, bk, (f32x4){0.f,0.f,0.f,0.f}, 0, 0, 0);
        }
        int cxi[4], cyi[4];
        #pragma unroll
        for (int r = 0; r < 4; r++) { const int i = rbase + g * 4 + r; cxi[r] = cx[i]; cyi[r] = cy[i]; }
        float m[4] = {-1e30f, -1e30f, -1e30f, -1e30f};
        #pragma unroll
        for (int tj = 0; tj < 8; tj++) {
            const int j = tj * 16 + fr;
            const int cxj = cx[j], cyj = cy[j];
            #pragma unroll
            for (int r = 0; r < 4; r++) {
                int dx = cxi[r] - cxj; dx = dx < 0 ? -dx : dx;
                int dy = cyi[r] - cyj; dy = dy < 0 ? -dy : dy;
                const float v = ((dx > dy ? dx : dy) > 4) ? -1e9f : sc[tj][r] * SCALE;
                sc[tj][r] = v;
                m[r] = fmaxf(m[r], v);
            }
        }
        #pragma unroll
        for (int r = 0; r < 4; r++) {
            #pragma unroll
            for (int o = 1; o < 16; o <<= 1) m[r] = fmaxf(m[r], __shfl_xor(m[r], o));
        }
        float sm[4] = {0.f, 0.f, 0.f, 0.f};
        #pragma unroll
        for (int tj = 0; tj < 8; tj++) {
            #pragma unroll
            for (int r = 0; r < 4; r++) {
                const float e = __expf(sc[tj][r] - m[r]);
                sc[tj][r] = e;
                sm[r] += e;
            }
        }
        #pragma unroll
        for (int r = 0; r < 4; r++) {
            #pragma unroll
            for (int o = 1; o < 16; o <<= 1) sm[r] += __shfl_xor(sm[r], o);
        }
        float inv[4];
        #pragma unroll
        for (int r = 0; r < 4; r++) inv[r] = 1.0f / sm[r];
        #pragma unroll
        for (int tj = 0; tj < 8; tj++) {
            #pragma unroll
            for (int r = 0; r < 4; r++)
                Pb[(wave * 16 + g * 4 + r) * 132 + tj * 16 + fr] = f2bf(sc[tj][r] * inv[r]);
        }
        #pragma unroll
        for (int td = 0; td < 2; td++) {
            f32x4 o = (f32x4){0.f, 0.f, 0.f, 0.f};
            #pragma unroll
            for (int kk = 0; kk < 4; kk++) {
                bf16x8 pa = *(const bf16x8*)&Pb[(wave * 16 + fr) * 132 + kk * 32 + fko];
                bf16x8 bv = *(const bf16x8*)&Vt[(td * 16 + fr) * 136 + kk * 32 + fko];
                o = __builtin_amdgcn_mfma_f32_16x16x32_bf16(pa, bv, o, 0, 0, 0);
            }
            #pragma unroll
            for (int r = 0; r < 4; r++) {
                const int i = half * 64 + wave * 16 + g * 4 + r;
                const int d = td * 16 + fr;
                out[((size_t)(bt * SSP + i)) * DMODEL + h * HD + d] = f2bf(o[r]);
            }
        }
    }
}

// ---------------- temporal attention: window of <=4 keys, per-thread scalar -----------
__device__ __forceinline__ float dot32(const float* __restrict__ qr,
                                       const unsigned short* __restrict__ Kt, int j)
{
    float a = 0.f;
    #pragma unroll
    for (int d = 0; d < 32; d++) a += qr[d] * bf2f(Kt[d * 128 + j]);
    return a;
}

__global__ __launch_bounds__(128)
void attn_temporal(const unsigned short* __restrict__ qkv,  // [NTOK][768]
                   unsigned short* __restrict__ out)        // [NTOK][256]
{
    __shared__ unsigned short Kt[32 * 128], Vt[32 * 128];   // transposed [d][t]
    const int bs = blockIdx.x, h = blockIdx.y;
    const int b = bs >> 7, sp = bs & 127;
    const int tid = threadIdx.x;   // t index 0..127
    const size_t rb = ((size_t)b * 16384 + (size_t)tid * 128 + sp) * 768 + (size_t)h * HD;
    bf16x8 qreg[4];
    #pragma unroll
    for (int c = 0; c < 4; c++) {
        qreg[c] = *(const bf16x8*)(qkv + rb + c * 8);
        bf16x8 k = *(const bf16x8*)(qkv + rb + 256 + c * 8);
        bf16x8 v = *(const bf16x8*)(qkv + rb + 512 + c * 8);
        #pragma unroll
        for (int e = 0; e < 8; e++) {
            const int d = c * 8 + e;
            Kt[d * 128 + tid] = (unsigned short)k[e];
            Vt[d * 128 + tid] = (unsigned short)v[e];
        }
    }
    __syncthreads();

    const int i = tid;
    float qr[32];
    #pragma unroll
    for (int d = 0; d < 32; d++) qr[d] = bf2f((unsigned short)qreg[d >> 3][d & 7]);

    float s0 = -1e30f, s1 = -1e30f, s2 = -1e30f;
    if (i >= 3) s0 = dot32(qr, Kt, i - 3) * SCALE;
    if (i >= 2) s1 = dot32(qr, Kt, i - 2) * SCALE;
    if (i >= 1) s2 = dot32(qr, Kt, i - 1) * SCALE;
    const float s3 = dot32(qr, Kt, i) * SCALE;

    const float mx = fmaxf(fmaxf(s0, s1), fmaxf(s2, s3));
    const float p0 = __expf(s0 - mx), p1 = __expf(s1 - mx), p2 = __expf(s2 - mx), p3 = __expf(s3 - mx);
    const float inv = 1.0f / (p0 + p1 + p2 + p3);
    const int j0 = i >= 3 ? i - 3 : 0;
    const int j1 = i >= 2 ? i - 2 : 0;
    const int j2 = i >= 1 ? i - 1 : 0;
    const size_t ob = ((size_t)b * 16384 + (size_t)i * 128 + sp) * DMODEL + (size_t)h * HD;
    #pragma unroll
    for (int d = 0; d < 32; d++) {
        const float o = (p0 * bf2f(Vt[d * 128 + j0]) + p1 * bf2f(Vt[d * 128 + j1]) +
                         p2 * bf2f(Vt[d * 128 + j2]) + p3 * bf2f(Vt[d * 128 + i])) * inv;
        out[ob + d] = f2bf(o);
    }
}

// --------------------------------------------------------------------------------------
extern "C" void kernel_launch(void* const* d_in, const int* in_sizes, int n_in,
                              void* d_out, int out_size, void* d_ws, size_t ws_size,
                              hipStream_t stream)
{
    const float* x_in   = (const float*)d_in[0];
    const int*   coords = (const int*)d_in[1];
    const float* Wqkv_s = (const float*)d_in[3];
    const float* bqkv_s = (const float*)d_in[4];
    const float* Wo_s   = (const float*)d_in[5];
    const float* bo_s   = (const float*)d_in[6];
    const float* Wqkv_t = (const float*)d_in[7];
    const float* bqkv_t = (const float*)d_in[8];
    const float* Wo_t   = (const float*)d_in[9];
    const float* bo_t   = (const float*)d_in[10];
    const float* g1     = (const float*)d_in[11];
    const float* g2     = (const float*)d_in[12];
    const float* g3     = (const float*)d_in[13];
    const float* W1     = (const float*)d_in[14];
    const float* b1     = (const float*)d_in[15];
    const float* W2     = (const float*)d_in[16];
    const float* b2     = (const float*)d_in[17];
    float* xo = (float*)d_out;

    char* ws = (char*)d_ws;
    unsigned short* wb  = (unsigned short*)ws;                                 // 2 MB weights
    unsigned short* xn  = (unsigned short*)(ws + (size_t)2 * 1024 * 1024);     // 32 MiB norm / attn-out
    unsigned short* big = (unsigned short*)(ws + (size_t)34 * 1024 * 1024);    // 96 MiB qkv / ffn-hidden

    unsigned short* wQKVs = wb;
    unsigned short* wOs   = wb + 196608;
    unsigned short* wQKVt = wb + 262144;
    unsigned short* wOt   = wb + 458752;
    unsigned short* w1b   = wb + 524288;
    unsigned short* w2b   = wb + 786432;

    cvt_w<<<4096, 256, 0, stream>>>(Wqkv_s, Wo_s, Wqkv_t, Wo_t, W1, W2, wb);

    // ---- spatial block ----
    rms_copy<<<16384, 256, 0, stream>>>(x_in, g1, xo, xn);
    gemm_bt<0><<<3072, 256, 0, stream>>>(xn, wQKVs, bqkv_s, big, nullptr, 768, 256, 6);
    attn_spatial<<<dim3(512, 8), 256, 0, stream>>>(big, coords, xn);
    gemm_rms<<<1024, 256, 0, stream>>>(xn, wOs, bo_s, xo, g2, xn, 256);

    // ---- temporal block ----
    gemm_bt<0><<<3072, 256, 0, stream>>>(xn, wQKVt, bqkv_t, big, nullptr, 768, 256, 6);
    attn_temporal<<<dim3(512, 8), 128, 0, stream>>>(big, xn);
    gemm_rms<<<1024, 256, 0, stream>>>(xn, wOt, bo_t, xo, g3, xn, 256);

    // ---- FFN block ----
    gemm_bt<1><<<4096, 256, 0, stream>>>(xn, w1b, b1, big, nullptr, 1024, 256, 8);
    gemm_bt<2><<<1024, 256, 0, stream>>>(big, w2b, b2, nullptr, xo, 256, 1024, 2);
}

// Round 6
// 559.645 us; speedup vs baseline: 1.6812x; 1.1455x over previous
//
#include <hip/hip_runtime.h>
#include <hip/hip_bf16.h>

typedef __attribute__((ext_vector_type(4))) float f32x4;
typedef __attribute__((ext_vector_type(8))) short bf16x8;
typedef __attribute__((ext_vector_type(4))) unsigned short u16x4;

#define NTOK 65536
#define DMODEL 256
#define DFF 1024
#define NH 8
#define HD 32
#define SSP 128
#define TLEN 128
#define SCALE 0.17677669529663687f  /* 1/sqrt(32) */

__device__ __forceinline__ float bf2f(unsigned short u) {
    return __builtin_bit_cast(float, (unsigned int)u << 16);
}
__device__ __forceinline__ unsigned short f2bf(float f) {
    unsigned int u = __builtin_bit_cast(unsigned int, f);
    unsigned int r = u + 0x7fffu + ((u >> 16) & 1u);
    return (unsigned short)(r >> 16);
}
__device__ __forceinline__ void gload_lds16(const void* g, void* l) {
    __builtin_amdgcn_global_load_lds((const __attribute__((address_space(1))) void*)g,
                                     (__attribute__((address_space(3))) void*)l, 16, 0, 0);
}

// ---------------- weight fp32 -> bf16 conversion (all 6 mats, 1,048,576 elems) --------
__global__ __launch_bounds__(256)
void cvt_w(const float* __restrict__ a, const float* __restrict__ b,
           const float* __restrict__ c, const float* __restrict__ d,
           const float* __restrict__ e, const float* __restrict__ f,
           unsigned short* __restrict__ o)
{
    int i = blockIdx.x * 256 + threadIdx.x;
    float v;
    if      (i < 196608)  v = a[i];
    else if (i < 262144)  v = b[i - 196608];
    else if (i < 458752)  v = c[i - 262144];
    else if (i < 524288)  v = d[i - 458752];
    else if (i < 786432)  v = e[i - 524288];
    else                  v = f[i - 786432];
    o[i] = f2bf(v);
}

// ---------------- copy x -> residual (fp32) + rmsnorm -> bf16, one wave per row -------
__global__ __launch_bounds__(256)
void rms_copy(const float* __restrict__ x, const float* __restrict__ g,
              float* __restrict__ xo, unsigned short* __restrict__ xn)
{
    const int row = blockIdx.x * 4 + (threadIdx.x >> 6);
    const int lane = threadIdx.x & 63;
    const float4 v = *(const float4*)&x[(size_t)row * DMODEL + lane * 4];
    float s = v.x * v.x + v.y * v.y + v.z * v.z + v.w * v.w;
    #pragma unroll
    for (int o = 1; o < 64; o <<= 1) s += __shfl_xor(s, o);
    const float rinv = rsqrtf(s * (1.0f / DMODEL) + 1.1920929e-7f);
    *(float4*)&xo[(size_t)row * DMODEL + lane * 4] = v;
    const float4 gv = *(const float4*)&g[lane * 4];
    u16x4 o4;
    o4[0] = f2bf(v.x * rinv * gv.x);
    o4[1] = f2bf(v.y * rinv * gv.y);
    o4[2] = f2bf(v.z * rinv * gv.z);
    o4[3] = f2bf(v.w * rinv * gv.w);
    *(u16x4*)&xn[(size_t)row * DMODEL + lane * 4] = o4;
}

// ---------------- GEMM: C[M,N] = A[M,K] * W[N,K]^T + bias (both bf16 row-major) -------
// BK=64, XOR-swizzled LDS; 1D grid, XCD-bijective swizzle, col-tile fastest.
// EPI 0: bias -> bf16 out; EPI 2: fp32 residual +=
template<int EPI>
__global__ __launch_bounds__(256)
void gemm_bt(const unsigned short* __restrict__ A,
             const unsigned short* __restrict__ W,
             const float* __restrict__ bias,
             unsigned short* __restrict__ Cb,
             float* __restrict__ Cf,
             int N, int K, int NCT)
{
    __shared__ unsigned short lds[17408];    // staging 32KB; epilogue reuse [128][136]
    unsigned short* As = lds;                // [128][64]
    unsigned short* Bs = lds + 8192;         // [128][64]

    const int tid = threadIdx.x;
    const int wave = tid >> 6, lane = tid & 63;
    const int wr = wave >> 1, wc = wave & 1;

    const int nwg = gridDim.x;
    const int bid = blockIdx.x;
    const int lin = (bid & 7) * (nwg >> 3) + (bid >> 3);   // nwg % 8 == 0
    const int row0 = (lin / NCT) * 128;
    const int col0 = (lin % NCT) * 128;

    f32x4 acc[4][4];
    #pragma unroll
    for (int i = 0; i < 4; i++)
        #pragma unroll
        for (int j = 0; j < 4; j++)
            acc[i][j] = (f32x4){0.f, 0.f, 0.f, 0.f};

    const int srow  = tid >> 3;                            // 0..31
    const int kx    = ((tid & 7) * 8) ^ ((srow & 7) * 8);  // swizzled source k-elem

    const int fr = lane & 15, g = lane >> 4;
    const int sw = (fr & 7) * 8;                           // read-side XOR

    for (int k0 = 0; k0 < K; k0 += 64) {
        #pragma unroll
        for (int q = 0; q < 4; q++) {
            const int row = q * 32 + srow;
            gload_lds16(A + (size_t)(row0 + row) * K + k0 + kx, As + q * 2048 + tid * 8);
            gload_lds16(W + (size_t)(col0 + row) * K + k0 + kx, Bs + q * 2048 + tid * 8);
        }
        __syncthreads();
        #pragma unroll
        for (int kh = 0; kh < 2; kh++) {
            const int ke = (kh * 32 + g * 8) ^ sw;
            bf16x8 af[4], bw[4];
            #pragma unroll
            for (int i = 0; i < 4; i++)
                af[i] = *(const bf16x8*)&As[(wr * 64 + i * 16 + fr) * 64 + ke];
            #pragma unroll
            for (int j = 0; j < 4; j++)
                bw[j] = *(const bf16x8*)&Bs[(wc * 64 + j * 16 + fr) * 64 + ke];
            #pragma unroll
            for (int i = 0; i < 4; i++)
                #pragma unroll
                for (int j = 0; j < 4; j++)
                    acc[i][j] = __builtin_amdgcn_mfma_f32_16x16x32_bf16(af[i], bw[j], acc[i][j], 0, 0, 0);
        }
        __syncthreads();
    }

    if constexpr (EPI == 2) {
        #pragma unroll
        for (int i = 0; i < 4; i++) {
            #pragma unroll
            for (int j = 0; j < 4; j++) {
                const int col = col0 + wc * 64 + j * 16 + fr;
                const float bv = bias[col];
                #pragma unroll
                for (int r = 0; r < 4; r++) {
                    const int row = row0 + wr * 64 + i * 16 + g * 4 + r;
                    Cf[(size_t)row * N + col] += acc[i][j][r] + bv;
                }
            }
        }
    } else {
        #pragma unroll
        for (int i = 0; i < 4; i++) {
            #pragma unroll
            for (int j = 0; j < 4; j++) {
                const int col = wc * 64 + j * 16 + fr;
                const float bv = bias[col0 + col];
                #pragma unroll
                for (int r = 0; r < 4; r++) {
                    float v = acc[i][j][r] + bv;
                    lds[(wr * 64 + i * 16 + g * 4 + r) * 136 + col] = f2bf(v);
                }
            }
        }
        __syncthreads();
        #pragma unroll
        for (int q = 0; q < 8; q++) {
            const int chunk = q * 256 + tid;
            const int row = chunk >> 4, c16 = chunk & 15;
            *(bf16x8*)&Cb[(size_t)(row0 + row) * N + col0 + c16 * 8] =
                *(const bf16x8*)&lds[row * 136 + c16 * 8];
        }
    }
}

// ---------------- fused GEMM + residual += + rmsnorm (full-row tile 64x256) -----------
// xo[row] += A*W^T + bias; xn[row] = rmsnorm(xo[row]) * g
__global__ __launch_bounds__(256)
void gemm_rms(const unsigned short* __restrict__ A,
              const unsigned short* __restrict__ W,
              const float* __restrict__ bias,
              float* __restrict__ xo,
              const float* __restrict__ gv,
              unsigned short* __restrict__ xn,
              int K)
{
    __shared__ unsigned short As[64 * 64];    // 8 KB
    __shared__ unsigned short Bs[256 * 64];   // 32 KB
    __shared__ float red[64 * 4];             // per-row per-wave partial sums

    const int tid = threadIdx.x;
    const int wave = tid >> 6, lane = tid & 63;
    const int fr = lane & 15, g4 = lane >> 4;

    const int nwg = gridDim.x;
    const int bid = blockIdx.x;
    const int lin = (bid & 7) * (nwg >> 3) + (bid >> 3);
    const int row0 = lin * 64;

    f32x4 acc[4][4];
    #pragma unroll
    for (int i = 0; i < 4; i++)
        #pragma unroll
        for (int j = 0; j < 4; j++)
            acc[i][j] = (f32x4){0.f, 0.f, 0.f, 0.f};

    const int srow = tid >> 3;
    const int kx   = ((tid & 7) * 8) ^ ((srow & 7) * 8);
    const int sw   = (fr & 7) * 8;

    for (int k0 = 0; k0 < K; k0 += 64) {
        #pragma unroll
        for (int p = 0; p < 2; p++)
            gload_lds16(A + (size_t)(row0 + p * 32 + srow) * K + k0 + kx, As + p * 2048 + tid * 8);
        #pragma unroll
        for (int p = 0; p < 8; p++)
            gload_lds16(W + (size_t)(p * 32 + srow) * K + k0 + kx, Bs + p * 2048 + tid * 8);
        __syncthreads();
        #pragma unroll
        for (int kh = 0; kh < 2; kh++) {
            const int ke = (kh * 32 + g4 * 8) ^ sw;
            bf16x8 af[4], bw[4];
            #pragma unroll
            for (int i = 0; i < 4; i++)
                af[i] = *(const bf16x8*)&As[(i * 16 + fr) * 64 + ke];
            #pragma unroll
            for (int j = 0; j < 4; j++)
                bw[j] = *(const bf16x8*)&Bs[(wave * 64 + j * 16 + fr) * 64 + ke];
            #pragma unroll
            for (int i = 0; i < 4; i++)
                #pragma unroll
                for (int j = 0; j < 4; j++)
                    acc[i][j] = __builtin_amdgcn_mfma_f32_16x16x32_bf16(af[i], bw[j], acc[i][j], 0, 0, 0);
        }
        __syncthreads();
    }

    #pragma unroll
    for (int i = 0; i < 4; i++) {
        #pragma unroll
        for (int j = 0; j < 4; j++) {
            const int col = wave * 64 + j * 16 + fr;
            const float bv = bias[col];
            #pragma unroll
            for (int r = 0; r < 4; r++) {
                const int row = row0 + i * 16 + g4 * 4 + r;
                const float xv = xo[(size_t)row * DMODEL + col] + acc[i][j][r] + bv;
                xo[(size_t)row * DMODEL + col] = xv;
                acc[i][j][r] = xv;
            }
        }
    }
    #pragma unroll
    for (int i = 0; i < 4; i++) {
        #pragma unroll
        for (int r = 0; r < 4; r++) {
            float p = acc[i][0][r] * acc[i][0][r] + acc[i][1][r] * acc[i][1][r]
                    + acc[i][2][r] * acc[i][2][r] + acc[i][3][r] * acc[i][3][r];
            #pragma unroll
            for (int o = 1; o < 16; o <<= 1) p += __shfl_xor(p, o);
            if (fr == 0) red[(i * 16 + g4 * 4 + r) * 4 + wave] = p;
        }
    }
    __syncthreads();
    #pragma unroll
    for (int i = 0; i < 4; i++) {
        #pragma unroll
        for (int r = 0; r < 4; r++) {
            const int rl = i * 16 + g4 * 4 + r;
            const float rsq = red[rl * 4 + 0] + red[rl * 4 + 1] + red[rl * 4 + 2] + red[rl * 4 + 3];
            const float rinv = rsqrtf(rsq * (1.0f / DMODEL) + 1.1920929e-7f);
            #pragma unroll
            for (int j = 0; j < 4; j++) {
                const int col = wave * 64 + j * 16 + fr;
                xn[(size_t)(row0 + rl) * DMODEL + col] = f2bf(acc[i][j][r] * rinv * gv[col]);
            }
        }
    }
}

// ---------------- fused FFN: xo += GELU(A*W1^T+b1)*W2^T + b2, 64-row tiles ------------
// 4 hidden chunks of 256: GEMM1 -> GELU(erff) -> H in LDS -> GEMM2 accumulate.
// LDS ~73 KB -> 2 blocks/CU. H padded to 264 elems/row (2-way bank = free).
__global__ __launch_bounds__(256)
void ffn_fused(const unsigned short* __restrict__ A,   // xn [NTOK][256]
               const unsigned short* __restrict__ W1,  // [1024][256] bf16
               const float* __restrict__ b1,
               const unsigned short* __restrict__ W2,  // [256][1024] bf16
               const float* __restrict__ b2,
               float* __restrict__ xo)
{
    __shared__ unsigned short As[64 * 64];      // 8 KB (BK=64 slice of A rows)
    __shared__ unsigned short Bs[256 * 64];     // 32 KB
    __shared__ unsigned short Hs[64 * 264];     // 33 KB, padded rows

    const int tid = threadIdx.x;
    const int wave = tid >> 6, lane = tid & 63;
    const int fr = lane & 15, g = lane >> 4;

    const int nwg = gridDim.x;
    const int bid = blockIdx.x;
    const int lin = (bid & 7) * (nwg >> 3) + (bid >> 3);
    const int row0 = lin * 64;

    const int srow = tid >> 3;                             // 0..31
    const int kx   = ((tid & 7) * 8) ^ ((srow & 7) * 8);   // swizzled source k
    const int sw   = (fr & 7) * 8;                         // read-side XOR

    f32x4 acc2[4][4];
    #pragma unroll
    for (int i = 0; i < 4; i++)
        #pragma unroll
        for (int j = 0; j < 4; j++)
            acc2[i][j] = (f32x4){0.f, 0.f, 0.f, 0.f};

    for (int c = 0; c < 4; c++) {
        // ---- GEMM1: accH = A[64x256] * W1_c[256x256]^T ----
        f32x4 accH[4][4];
        #pragma unroll
        for (int i = 0; i < 4; i++)
            #pragma unroll
            for (int j = 0; j < 4; j++)
                accH[i][j] = (f32x4){0.f, 0.f, 0.f, 0.f};

        for (int k0 = 0; k0 < 256; k0 += 64) {
            #pragma unroll
            for (int p = 0; p < 2; p++)
                gload_lds16(A + (size_t)(row0 + p * 32 + srow) * DMODEL + k0 + kx,
                            As + p * 2048 + tid * 8);
            #pragma unroll
            for (int p = 0; p < 8; p++)
                gload_lds16(W1 + (size_t)(c * 256 + p * 32 + srow) * DMODEL + k0 + kx,
                            Bs + p * 2048 + tid * 8);
            __syncthreads();
            #pragma unroll
            for (int kh = 0; kh < 2; kh++) {
                const int ke = (kh * 32 + g * 8) ^ sw;
                bf16x8 af[4], bw[4];
                #pragma unroll
                for (int i = 0; i < 4; i++)
                    af[i] = *(const bf16x8*)&As[(i * 16 + fr) * 64 + ke];
                #pragma unroll
                for (int j = 0; j < 4; j++)
                    bw[j] = *(const bf16x8*)&Bs[(wave * 64 + j * 16 + fr) * 64 + ke];
                #pragma unroll
                for (int i = 0; i < 4; i++)
                    #pragma unroll
                    for (int j = 0; j < 4; j++)
                        accH[i][j] = __builtin_amdgcn_mfma_f32_16x16x32_bf16(af[i], bw[j], accH[i][j], 0, 0, 0);
            }
            __syncthreads();
        }

        // ---- GELU (erff) + write H chunk to LDS ----
        #pragma unroll
        for (int j = 0; j < 4; j++) {
            const int col = wave * 64 + j * 16 + fr;
            const float bv = b1[c * 256 + col];
            #pragma unroll
            for (int i = 0; i < 4; i++) {
                #pragma unroll
                for (int r = 0; r < 4; r++) {
                    float v = accH[i][j][r] + bv;
                    v = 0.5f * v * (1.0f + erff(v * 0.70710678118654752f));
                    Hs[(i * 16 + g * 4 + r) * 264 + col] = f2bf(v);
                }
            }
        }
        __syncthreads();

        // ---- GEMM2: acc2 += H[64x256] * W2_c[256x256]^T ----
        for (int k0 = 0; k0 < 256; k0 += 64) {
            #pragma unroll
            for (int p = 0; p < 8; p++)
                gload_lds16(W2 + (size_t)(p * 32 + srow) * DFF + c * 256 + k0 + kx,
                            Bs + p * 2048 + tid * 8);
            __syncthreads();
            #pragma unroll
            for (int kh = 0; kh < 2; kh++) {
                const int keh = k0 + kh * 32 + g * 8;         // H: padded, no XOR
                const int ke  = (kh * 32 + g * 8) ^ sw;       // Bs: XOR swizzle
                bf16x8 ha[4], bw[4];
                #pragma unroll
                for (int i = 0; i < 4; i++)
                    ha[i] = *(const bf16x8*)&Hs[(i * 16 + fr) * 264 + keh];
                #pragma unroll
                for (int j = 0; j < 4; j++)
                    bw[j] = *(const bf16x8*)&Bs[(wave * 64 + j * 16 + fr) * 64 + ke];
                #pragma unroll
                for (int i = 0; i < 4; i++)
                    #pragma unroll
                    for (int j = 0; j < 4; j++)
                        acc2[i][j] = __builtin_amdgcn_mfma_f32_16x16x32_bf16(ha[i], bw[j], acc2[i][j], 0, 0, 0);
            }
            __syncthreads();
        }
    }

    // ---- epilogue: fp32 residual RMW ----
    #pragma unroll
    for (int j = 0; j < 4; j++) {
        const int col = wave * 64 + j * 16 + fr;
        const float bv = b2[col];
        #pragma unroll
        for (int i = 0; i < 4; i++) {
            #pragma unroll
            for (int r = 0; r < 4; r++) {
                const int row = row0 + i * 16 + g * 4 + r;
                xo[(size_t)row * DMODEL + col] += acc2[i][j][r] + bv;
            }
        }
    }
}

// ---------------- spatial attention: one block per (bt, head), 128x128, MFMA ----------
__global__ __launch_bounds__(256)
void attn_spatial(const unsigned short* __restrict__ qkv,  // [NTOK][768]
                  const int* __restrict__ coords,          // [128][2]
                  unsigned short* __restrict__ out)        // [NTOK][256]
{
    __shared__ unsigned short Qs[128 * 32];
    __shared__ unsigned short Ks[128 * 32];
    __shared__ unsigned short Vt[32 * 136];   // V^T, padded rows
    __shared__ unsigned short Pb[64 * 132];   // bf16 P for one 64-row half
    __shared__ int cx[128], cy[128];

    const int bt = blockIdx.x, h = blockIdx.y;
    const int tid = threadIdx.x, wave = tid >> 6, lane = tid & 63;
    const size_t base = (size_t)bt * SSP * 768 + (size_t)h * HD;

    {   // stage Q,K (row-major [128][32]) and V transposed
        const int rr = tid >> 1, cb = (tid & 1) * 16;
        const unsigned short* p = qkv + base + (size_t)rr * 768 + cb;
        *(bf16x8*)&Qs[rr * 32 + cb]     = *(const bf16x8*)p;
        *(bf16x8*)&Qs[rr * 32 + cb + 8] = *(const bf16x8*)(p + 8);
        p += 256;
        *(bf16x8*)&Ks[rr * 32 + cb]     = *(const bf16x8*)p;
        *(bf16x8*)&Ks[rr * 32 + cb + 8] = *(const bf16x8*)(p + 8);
        p += 256;
        bf16x8 v0 = *(const bf16x8*)p, v1 = *(const bf16x8*)(p + 8);
        #pragma unroll
        for (int e = 0; e < 8; e++) {
            Vt[(cb + e) * 136 + rr]     = (unsigned short)v0[e];
            Vt[(cb + 8 + e) * 136 + rr] = (unsigned short)v1[e];
        }
        if (tid < 128) { cx[tid] = coords[2 * tid]; cy[tid] = coords[2 * tid + 1]; }
    }
    __syncthreads();

    const int fr = lane & 15;
    const int g  = lane >> 4;
    const int fko = g * 8;

    for (int half = 0; half < 2; half++) {
        const int rbase = half * 64 + wave * 16;
        bf16x8 aq = *(const bf16x8*)&Qs[(rbase + fr) * 32 + fko];
        f32x4 sc[8];
        #pragma unroll
        for (int tj = 0; tj < 8; tj++) {
            bf16x8 bk = *(const bf16x8*)&Ks[(tj * 16 + fr) * 32 + fko];
            sc[tj] = __builtin_amdgcn_mfma_f32_16x16x32_bf16(aq, bk, (f32x4){0.f,0.f,0.f,0.f}, 0, 0, 0);
        }
        int cxi[4], cyi[4];
        #pragma unroll
        for (int r = 0; r < 4; r++) { const int i = rbase + g * 4 + r; cxi[r] = cx[i]; cyi[r] = cy[i]; }
        float m[4] = {-1e30f, -1e30f, -1e30f, -1e30f};
        #pragma unroll
        for (int tj = 0; tj < 8; tj++) {
            const int j = tj * 16 + fr;
            const int cxj = cx[j], cyj = cy[j];
            #pragma unroll
            for (int r = 0; r < 4; r++) {
                int dx = cxi[r] - cxj; dx = dx < 0 ? -dx : dx;
                int dy = cyi[r] - cyj; dy = dy < 0 ? -dy : dy;
                const float v = ((dx > dy ? dx : dy) > 4) ? -1e9f : sc[tj][r] * SCALE;
                sc[tj][r] = v;
                m[r] = fmaxf(m[r], v);
            }
        }
        #pragma unroll
        for (int r = 0; r < 4; r++) {
            #pragma unroll
            for (int o = 1; o < 16; o <<= 1) m[r] = fmaxf(m[r], __shfl_xor(m[r], o));
        }
        float sm[4] = {0.f, 0.f, 0.f, 0.f};
        #pragma unroll
        for (int tj = 0; tj < 8; tj++) {
            #pragma unroll
            for (int r = 0; r < 4; r++) {
                const float e = __expf(sc[tj][r] - m[r]);
                sc[tj][r] = e;
                sm[r] += e;
            }
        }
        #pragma unroll
        for (int r = 0; r < 4; r++) {
            #pragma unroll
            for (int o = 1; o < 16; o <<= 1) sm[r] += __shfl_xor(sm[r], o);
        }
        float inv[4];
        #pragma unroll
        for (int r = 0; r < 4; r++) inv[r] = 1.0f / sm[r];
        #pragma unroll
        for (int tj = 0; tj < 8; tj++) {
            #pragma unroll
            for (int r = 0; r < 4; r++)
                Pb[(wave * 16 + g * 4 + r) * 132 + tj * 16 + fr] = f2bf(sc[tj][r] * inv[r]);
        }
        #pragma unroll
        for (int td = 0; td < 2; td++) {
            f32x4 o = (f32x4){0.f, 0.f, 0.f, 0.f};
            #pragma unroll
            for (int kk = 0; kk < 4; kk++) {
                bf16x8 pa = *(const bf16x8*)&Pb[(wave * 16 + fr) * 132 + kk * 32 + fko];
                bf16x8 bv = *(const bf16x8*)&Vt[(td * 16 + fr) * 136 + kk * 32 + fko];
                o = __builtin_amdgcn_mfma_f32_16x16x32_bf16(pa, bv, o, 0, 0, 0);
            }
            #pragma unroll
            for (int r = 0; r < 4; r++) {
                const int i = half * 64 + wave * 16 + g * 4 + r;
                const int d = td * 16 + fr;
                out[((size_t)(bt * SSP + i)) * DMODEL + h * HD + d] = f2bf(o[r]);
            }
        }
    }
}

// ---------------- temporal attention: window of <=4 keys, per-thread scalar -----------
__device__ __forceinline__ float dot32(const float* __restrict__ qr,
                                       const unsigned short* __restrict__ Kt, int j)
{
    float a = 0.f;
    #pragma unroll
    for (int d = 0; d < 32; d++) a += qr[d] * bf2f(Kt[d * 128 + j]);
    return a;
}

__global__ __launch_bounds__(128)
void attn_temporal(const unsigned short* __restrict__ qkv,  // [NTOK][768]
                   unsigned short* __restrict__ out)        // [NTOK][256]
{
    __shared__ unsigned short Kt[32 * 128], Vt[32 * 128];   // transposed [d][t]
    const int bs = blockIdx.x, h = blockIdx.y;
    const int b = bs >> 7, sp = bs & 127;
    const int tid = threadIdx.x;   // t index 0..127
    const size_t rb = ((size_t)b * 16384 + (size_t)tid * 128 + sp) * 768 + (size_t)h * HD;
    bf16x8 qreg[4];
    #pragma unroll
    for (int c = 0; c < 4; c++) {
        qreg[c] = *(const bf16x8*)(qkv + rb + c * 8);
        bf16x8 k = *(const bf16x8*)(qkv + rb + 256 + c * 8);
        bf16x8 v = *(const bf16x8*)(qkv + rb + 512 + c * 8);
        #pragma unroll
        for (int e = 0; e < 8; e++) {
            const int d = c * 8 + e;
            Kt[d * 128 + tid] = (unsigned short)k[e];
            Vt[d * 128 + tid] = (unsigned short)v[e];
        }
    }
    __syncthreads();

    const int i = tid;
    float qr[32];
    #pragma unroll
    for (int d = 0; d < 32; d++) qr[d] = bf2f((unsigned short)qreg[d >> 3][d & 7]);

    float s0 = -1e30f, s1 = -1e30f, s2 = -1e30f;
    if (i >= 3) s0 = dot32(qr, Kt, i - 3) * SCALE;
    if (i >= 2) s1 = dot32(qr, Kt, i - 2) * SCALE;
    if (i >= 1) s2 = dot32(qr, Kt, i - 1) * SCALE;
    const float s3 = dot32(qr, Kt, i) * SCALE;

    const float mx = fmaxf(fmaxf(s0, s1), fmaxf(s2, s3));
    const float p0 = __expf(s0 - mx), p1 = __expf(s1 - mx), p2 = __expf(s2 - mx), p3 = __expf(s3 - mx);
    const float inv = 1.0f / (p0 + p1 + p2 + p3);
    const int j0 = i >= 3 ? i - 3 : 0;
    const int j1 = i >= 2 ? i - 2 : 0;
    const int j2 = i >= 1 ? i - 1 : 0;
    const size_t ob = ((size_t)b * 16384 + (size_t)i * 128 + sp) * DMODEL + (size_t)h * HD;
    #pragma unroll
    for (int d = 0; d < 32; d++) {
        const float o = (p0 * bf2f(Vt[d * 128 + j0]) + p1 * bf2f(Vt[d * 128 + j1]) +
                         p2 * bf2f(Vt[d * 128 + j2]) + p3 * bf2f(Vt[d * 128 + i])) * inv;
        out[ob + d] = f2bf(o);
    }
}

// --------------------------------------------------------------------------------------
extern "C" void kernel_launch(void* const* d_in, const int* in_sizes, int n_in,
                              void* d_out, int out_size, void* d_ws, size_t ws_size,
                              hipStream_t stream)
{
    const float* x_in   = (const float*)d_in[0];
    const int*   coords = (const int*)d_in[1];
    const float* Wqkv_s = (const float*)d_in[3];
    const float* bqkv_s = (const float*)d_in[4];
    const float* Wo_s   = (const float*)d_in[5];
    const float* bo_s   = (const float*)d_in[6];
    const float* Wqkv_t = (const float*)d_in[7];
    const float* bqkv_t = (const float*)d_in[8];
    const float* Wo_t   = (const float*)d_in[9];
    const float* bo_t   = (const float*)d_in[10];
    const float* g1     = (const float*)d_in[11];
    const float* g2     = (const float*)d_in[12];
    const float* g3     = (const float*)d_in[13];
    const float* W1     = (const float*)d_in[14];
    const float* b1     = (const float*)d_in[15];
    const float* W2     = (const float*)d_in[16];
    const float* b2     = (const float*)d_in[17];
    float* xo = (float*)d_out;

    char* ws = (char*)d_ws;
    unsigned short* wb  = (unsigned short*)ws;                                 // 2 MB weights
    unsigned short* xn  = (unsigned short*)(ws + (size_t)2 * 1024 * 1024);     // 32 MiB norm / attn-out
    unsigned short* big = (unsigned short*)(ws + (size_t)34 * 1024 * 1024);    // 96 MiB qkv

    unsigned short* wQKVs = wb;
    unsigned short* wOs   = wb + 196608;
    unsigned short* wQKVt = wb + 262144;
    unsigned short* wOt   = wb + 458752;
    unsigned short* w1b   = wb + 524288;
    unsigned short* w2b   = wb + 786432;

    cvt_w<<<4096, 256, 0, stream>>>(Wqkv_s, Wo_s, Wqkv_t, Wo_t, W1, W2, wb);

    // ---- spatial block ----
    rms_copy<<<16384, 256, 0, stream>>>(x_in, g1, xo, xn);
    gemm_bt<0><<<3072, 256, 0, stream>>>(xn, wQKVs, bqkv_s, big, nullptr, 768, 256, 6);
    attn_spatial<<<dim3(512, 8), 256, 0, stream>>>(big, coords, xn);
    gemm_rms<<<1024, 256, 0, stream>>>(xn, wOs, bo_s, xo, g2, xn, 256);

    // ---- temporal block ----
    gemm_bt<0><<<3072, 256, 0, stream>>>(xn, wQKVt, bqkv_t, big, nullptr, 768, 256, 6);
    attn_temporal<<<dim3(512, 8), 128, 0, stream>>>(big, xn);
    gemm_rms<<<1024, 256, 0, stream>>>(xn, wOt, bo_t, xo, g3, xn, 256);

    // ---- fused FFN ----
    ffn_fused<<<1024, 256, 0, stream>>>(xn, w1b, b1, w2b, b2, xo);
}